// Round 1
// baseline (803.835 us; speedup 1.0000x reference)
//
#include <hip/hip_runtime.h>
#include <cstdint>
#include <cstddef>

#define HD 128

// ---------------- layer-0 linears (fan-in = 2) ----------------
__global__ __launch_bounds__(256) void lin0_kernel(
    const float* __restrict__ x,
    const float* __restrict__ Wq, const float* __restrict__ bq,
    const float* __restrict__ Wk, const float* __restrict__ bk,
    const float* __restrict__ Wv, const float* __restrict__ bv,
    const float* __restrict__ Ws, const float* __restrict__ bs,
    float* __restrict__ qkvs, int n)
{
    int gid = blockIdx.x * 256 + threadIdx.x;
    if (gid >= n * HD) return;
    int i = gid >> 7, j = gid & 127;
    float x0 = x[2 * i], x1 = x[2 * i + 1];
    size_t nd = (size_t)n * HD;
    qkvs[gid]          = fmaf(x1, Wq[HD + j], fmaf(x0, Wq[j], bq[j]));
    qkvs[nd + gid]     = fmaf(x1, Wk[HD + j], fmaf(x0, Wk[j], bk[j]));
    qkvs[2 * nd + gid] = fmaf(x1, Wv[HD + j], fmaf(x0, Wv[j], bv[j]));
    qkvs[3 * nd + gid] = fmaf(x1, Ws[HD + j], fmaf(x0, Ws[j], bs[j]));
}

// ---------------- CSR-by-dst build ----------------
__global__ __launch_bounds__(256) void hist_kernel(
    const int* __restrict__ dst, int* __restrict__ cnt, int E)
{
    int e = blockIdx.x * 256 + threadIdx.x;
    if (e < E) atomicAdd(&cnt[dst[e]], 1);
}

__global__ __launch_bounds__(1024) void scan_kernel(
    const int* __restrict__ cnt, int* __restrict__ row_ptr,
    int* __restrict__ cursor, int n)
{
    __shared__ int sdata[1024];
    int t = threadIdx.x;
    int CH = (n + 1023) >> 10;
    int lo = t * CH;
    int hi = lo + CH; if (hi > n) hi = n;
    int local = 0;
    for (int i = lo; i < hi; ++i) local += cnt[i];
    sdata[t] = local;
    __syncthreads();
    for (int off = 1; off < 1024; off <<= 1) {
        int val = (t >= off) ? sdata[t - off] : 0;
        __syncthreads();
        sdata[t] += val;
        __syncthreads();
    }
    int run = sdata[t] - local;   // exclusive prefix of this thread's chunk
    for (int i = lo; i < hi; ++i) {
        row_ptr[i] = run; cursor[i] = run;
        run += cnt[i];
    }
    if (t == 1023) row_ptr[n] = run;
}

__global__ __launch_bounds__(256) void scatter_kernel(
    const int* __restrict__ dst, int* __restrict__ cursor,
    int* __restrict__ edge_ids, int E)
{
    int e = blockIdx.x * 256 + threadIdx.x;
    if (e < E) {
        int pos = atomicAdd(&cursor[dst[e]], 1);
        edge_ids[pos] = e;
    }
}

// ---------------- attention (one wave per node, float2 per lane) ----------------
__global__ __launch_bounds__(256) void attn_kernel(
    const float* __restrict__ qkvs, const float* __restrict__ We,
    const float* __restrict__ eattr, const int* __restrict__ src,
    const int* __restrict__ row_ptr, const int* __restrict__ edge_ids,
    float* __restrict__ out, int n)
{
    int i = blockIdx.x * 4 + (threadIdx.x >> 6);
    if (i >= n) return;
    int l = threadIdx.x & 63;
    size_t nd = (size_t)n * HD;
    const float2* kb = (const float2*)(qkvs + nd);
    const float2* vb = (const float2*)(qkvs + 2 * nd);
    float2 q  = *(const float2*)&qkvs[(size_t)i * HD + 2 * l];
    float2 we = *(const float2*)&We[2 * l];
    int p0 = row_ptr[i], p1 = row_ptr[i + 1];
    float m = -INFINITY, s = 0.f;
    float2 acc = make_float2(0.f, 0.f);
    for (int p = p0; p < p1; ++p) {
        int e   = edge_ids[p];
        int sn  = src[e];
        float eav = eattr[e];
        float2 kj = kb[(size_t)sn * 64 + l];
        float2 vj = vb[(size_t)sn * 64 + l];
        kj.x = fmaf(eav, we.x, kj.x); kj.y = fmaf(eav, we.y, kj.y);
        vj.x = fmaf(eav, we.x, vj.x); vj.y = fmaf(eav, we.y, vj.y);
        float prod = fmaf(q.x, kj.x, q.y * kj.y);
        #pragma unroll
        for (int o = 16; o > 0; o >>= 1) prod += __shfl_xor(prod, o, 64);
        float logit = prod * 0.125f;          // / sqrt(64)
        float nm = fmaxf(m, logit);
        float sc = __expf(m - nm);            // first iter: exp(-inf)=0
        float ex = __expf(logit - nm);
        s     = fmaf(s, sc, ex);
        acc.x = fmaf(acc.x, sc, ex * vj.x);
        acc.y = fmaf(acc.y, sc, ex * vj.y);
        m = nm;
    }
    float inv = 1.f / (s + 1e-16f);
    float2 skp = *(const float2*)&qkvs[3 * nd + (size_t)i * HD + 2 * l];
    float2 res;
    res.x = fmaxf(fmaf(acc.x, inv, skp.x), 0.f);
    res.y = fmaxf(fmaf(acc.y, inv, skp.y), 0.f);
    *(float2*)&out[(size_t)i * HD + 2 * l] = res;
}

// ---------------- layer-1 linears: [n,128] @ [128,128] x4, f32 LDS-tiled ----------------
// BM=128 rows, BN=128 cols (one matrix per blockIdx.y), BK=64 (two stages).
// As stored transposed [k][r] with XOR swizzle to keep stores ~2-way / loads conflict-free.
__device__ __forceinline__ int a_idx(int k, int r) {
    return k * 128 + (r ^ (((k >> 2) & 7) << 2));
}

__global__ __launch_bounds__(256) void lin1_kernel(
    const float* __restrict__ A,
    const float* __restrict__ Wq, const float* __restrict__ bq,
    const float* __restrict__ Wk, const float* __restrict__ bk,
    const float* __restrict__ Wv, const float* __restrict__ bv,
    const float* __restrict__ Ws, const float* __restrict__ bs,
    float* __restrict__ qkvs, int n)
{
    __shared__ float As[64 * 128];   // 32 KB
    __shared__ float Bs[64 * 128];   // 32 KB
    const float* W; const float* b;
    int mat = blockIdx.y;
    if (mat == 0)      { W = Wq; b = bq; }
    else if (mat == 1) { W = Wk; b = bk; }
    else if (mat == 2) { W = Wv; b = bv; }
    else               { W = Ws; b = bs; }
    float* out = qkvs + (size_t)mat * n * HD;

    int tid = threadIdx.x;
    int row0 = blockIdx.x * 128;
    int tx = tid & 15, ty = tid >> 4;
    int mBase = ty * 8;
    int c0 = tx * 4, c1 = 64 + tx * 4;

    float acc0[8][4] = {};
    float acc1[8][4] = {};

    for (int kt = 0; kt < 2; ++kt) {
        int kOff = kt * 64;
        // stage A (transposed+swizzled) and B
        #pragma unroll
        for (int it = 0; it < 8; ++it) {
            int lin = (it * 256 + tid) * 4;
            int r = lin >> 6, k = lin & 63;        // A: 128 rows x 64 k
            float4 av;
            if (row0 + r < n) av = *(const float4*)&A[(size_t)(row0 + r) * HD + kOff + k];
            else              av = make_float4(0.f, 0.f, 0.f, 0.f);
            As[a_idx(k + 0, r)] = av.x;
            As[a_idx(k + 1, r)] = av.y;
            As[a_idx(k + 2, r)] = av.z;
            As[a_idx(k + 3, r)] = av.w;
            *(float4*)&Bs[lin] = *(const float4*)&W[kOff * 128 + lin];  // Bs[k][col]
        }
        __syncthreads();
        for (int k = 0; k < 64; ++k) {
            int sw = ((k >> 2) & 7) << 2;
            float4 a0 = *(const float4*)&As[k * 128 + (mBase ^ sw)];
            float4 a1 = *(const float4*)&As[k * 128 + ((mBase + 4) ^ sw)];
            float4 b0 = *(const float4*)&Bs[k * 128 + c0];
            float4 b1 = *(const float4*)&Bs[k * 128 + c1];
            float a[8] = {a0.x, a0.y, a0.z, a0.w, a1.x, a1.y, a1.z, a1.w};
            #pragma unroll
            for (int j = 0; j < 8; ++j) {
                acc0[j][0] = fmaf(a[j], b0.x, acc0[j][0]);
                acc0[j][1] = fmaf(a[j], b0.y, acc0[j][1]);
                acc0[j][2] = fmaf(a[j], b0.z, acc0[j][2]);
                acc0[j][3] = fmaf(a[j], b0.w, acc0[j][3]);
                acc1[j][0] = fmaf(a[j], b1.x, acc1[j][0]);
                acc1[j][1] = fmaf(a[j], b1.y, acc1[j][1]);
                acc1[j][2] = fmaf(a[j], b1.z, acc1[j][2]);
                acc1[j][3] = fmaf(a[j], b1.w, acc1[j][3]);
            }
        }
        __syncthreads();
    }

    float bb0[4] = {b[c0], b[c0 + 1], b[c0 + 2], b[c0 + 3]};
    float bb1[4] = {b[c1], b[c1 + 1], b[c1 + 2], b[c1 + 3]};
    #pragma unroll
    for (int j = 0; j < 8; ++j) {
        int rr = row0 + mBase + j;
        if (rr < n) {
            float4 o0 = make_float4(acc0[j][0] + bb0[0], acc0[j][1] + bb0[1],
                                    acc0[j][2] + bb0[2], acc0[j][3] + bb0[3]);
            float4 o1 = make_float4(acc1[j][0] + bb1[0], acc1[j][1] + bb1[1],
                                    acc1[j][2] + bb1[2], acc1[j][3] + bb1[3]);
            *(float4*)&out[(size_t)rr * HD + c0] = o0;
            *(float4*)&out[(size_t)rr * HD + c1] = o1;
        }
    }
}

// ---------------- mean-pool (batch sorted -> run-length partials) ----------------
__global__ __launch_bounds__(128) void pool_kernel(
    const float* __restrict__ h, const int* __restrict__ batch,
    float* __restrict__ gsums, float* __restrict__ gcnt, int n)
{
    __shared__ int sb[64];
    int i0 = blockIdx.x * 64;
    int d = threadIdx.x;               // 0..127 = feature dim
    int iend = i0 + 64; if (iend > n) iend = n;
    int csize = iend - i0;
    if (d < csize) sb[d] = batch[i0 + d];
    __syncthreads();
    if (csize <= 0) return;
    float local = 0.f;
    int cur = sb[0];
    int runc = 0;
    for (int i = i0; i < iend; ++i) {
        int g = sb[i - i0];
        if (g != cur) {
            atomicAdd(&gsums[(size_t)cur * HD + d], local);
            if (d == 0) atomicAdd(&gcnt[cur], (float)runc);
            local = 0.f; runc = 0; cur = g;
        }
        local += h[(size_t)i * HD + d];
        runc++;
    }
    atomicAdd(&gsums[(size_t)cur * HD + d], local);
    if (d == 0) atomicAdd(&gcnt[cur], (float)runc);
}

// ---------------- classifier head: one block per graph ----------------
__global__ __launch_bounds__(128) void cls_kernel(
    const float* __restrict__ gsums, const float* __restrict__ gcnt,
    const float* __restrict__ cW1, const float* __restrict__ cb1,
    const float* __restrict__ cW2, const float* __restrict__ cb2,
    float* __restrict__ out)
{
    __shared__ float g[128];
    __shared__ float t[128];
    int gi = blockIdx.x, j = threadIdx.x;
    float c = fmaxf(gcnt[gi], 1.0f);
    g[j] = gsums[(size_t)gi * HD + j] / c;
    __syncthreads();
    float a = cb1[j];
    for (int k = 0; k < 128; ++k) a = fmaf(g[k], cW1[k * 128 + j], a);
    t[j] = fmaxf(a, 0.f);
    __syncthreads();
    if (j < 30) {
        float a2 = cb2[j];
        for (int k = 0; k < 128; ++k) a2 = fmaf(t[k], cW2[k * 30 + j], a2);
        out[gi * 30 + j] = a2;
    }
}

extern "C" void kernel_launch(void* const* d_in, const int* in_sizes, int n_in,
                              void* d_out, int out_size, void* d_ws, size_t ws_size,
                              hipStream_t stream)
{
    const float* x     = (const float*)d_in[0];
    const int*   ei    = (const int*)d_in[1];
    const float* eattr = (const float*)d_in[2];
    const int*   batch = (const int*)d_in[3];
    const float* l0_Wq = (const float*)d_in[4];
    const float* l0_bq = (const float*)d_in[5];
    const float* l0_Wk = (const float*)d_in[6];
    const float* l0_bk = (const float*)d_in[7];
    const float* l0_Wv = (const float*)d_in[8];
    const float* l0_bv = (const float*)d_in[9];
    const float* l0_We = (const float*)d_in[10];
    const float* l0_Ws = (const float*)d_in[11];
    const float* l0_bs = (const float*)d_in[12];
    const float* l1_Wq = (const float*)d_in[13];
    const float* l1_bq = (const float*)d_in[14];
    const float* l1_Wk = (const float*)d_in[15];
    const float* l1_bk = (const float*)d_in[16];
    const float* l1_Wv = (const float*)d_in[17];
    const float* l1_bv = (const float*)d_in[18];
    const float* l1_We = (const float*)d_in[19];
    const float* l1_Ws = (const float*)d_in[20];
    const float* l1_bs = (const float*)d_in[21];
    const float* cW1   = (const float*)d_in[22];
    const float* cb1   = (const float*)d_in[23];
    const float* cW2   = (const float*)d_in[24];
    const float* cb2   = (const float*)d_in[25];

    int n = in_sizes[0] / 2;     // 50000
    int E = in_sizes[2];         // 800000 (edge_attr is [E,1])
    int G = out_size / 30;       // 64

    size_t nd = (size_t)n * HD;
    float* qkvs   = (float*)d_ws;                 // 4*n*128 f32
    float* h      = qkvs + 4 * nd;                // n*128 f32
    int* cnt      = (int*)(h + nd);               // n
    int* row_ptr  = cnt + n;                      // n+1
    int* cursor   = row_ptr + n + 1;              // n
    int* edge_ids = cursor + n;                   // E
    float* gsums  = (float*)(edge_ids + E);       // G*128
    float* gcnt   = gsums + (size_t)G * HD;       // G

    const int* srcI = ei;
    const int* dstI = ei + E;

    hipMemsetAsync(cnt, 0, (size_t)n * sizeof(int), stream);
    hipMemsetAsync(gsums, 0, ((size_t)G * HD + G) * sizeof(float), stream);

    hist_kernel<<<(E + 255) / 256, 256, 0, stream>>>(dstI, cnt, E);
    scan_kernel<<<1, 1024, 0, stream>>>(cnt, row_ptr, cursor, n);
    scatter_kernel<<<(E + 255) / 256, 256, 0, stream>>>(dstI, cursor, edge_ids, E);

    lin0_kernel<<<(n * HD + 255) / 256, 256, 0, stream>>>(
        x, l0_Wq, l0_bq, l0_Wk, l0_bk, l0_Wv, l0_bv, l0_Ws, l0_bs, qkvs, n);
    attn_kernel<<<(n + 3) / 4, 256, 0, stream>>>(
        qkvs, l0_We, eattr, srcI, row_ptr, edge_ids, h, n);

    lin1_kernel<<<dim3((n + 127) / 128, 4), 256, 0, stream>>>(
        h, l1_Wq, l1_bq, l1_Wk, l1_bk, l1_Wv, l1_bv, l1_Ws, l1_bs, qkvs, n);
    attn_kernel<<<(n + 3) / 4, 256, 0, stream>>>(
        qkvs, l1_We, eattr, srcI, row_ptr, edge_ids, h, n);

    pool_kernel<<<(n + 63) / 64, 128, 0, stream>>>(h, batch, gsums, gcnt, n);
    cls_kernel<<<G, 128, 0, stream>>>(gsums, gcnt, cW1, cb1, cW2, cb2, (float*)d_out);
}

// Round 2
// 756.634 us; speedup vs baseline: 1.0624x; 1.0624x over previous
//
#include <hip/hip_runtime.h>
#include <cstdint>
#include <cstddef>

#define HD 128

typedef short bf16x8 __attribute__((ext_vector_type(8)));   // 8 bf16 in 4 VGPRs
typedef float f32x4 __attribute__((ext_vector_type(4)));

__device__ __forceinline__ unsigned short f2bf(float f) {
    unsigned int u = __float_as_uint(f);
    u += 0x7fff + ((u >> 16) & 1);          // round-to-nearest-even
    return (unsigned short)(u >> 16);
}
__device__ __forceinline__ float bf2f(unsigned short h) {
    return __uint_as_float(((unsigned int)h) << 16);
}

// ---------------- layer-0 linears (fan-in = 2); writes q, interleaved kv, skip ----
// kv layout per node row (256 f32): lane l owns float4 (k_{2l},k_{2l+1},v_{2l},v_{2l+1})
__global__ __launch_bounds__(256) void lin0_kernel(
    const float* __restrict__ x,
    const float* __restrict__ Wq, const float* __restrict__ bq,
    const float* __restrict__ Wk, const float* __restrict__ bk,
    const float* __restrict__ Wv, const float* __restrict__ bv,
    const float* __restrict__ Ws, const float* __restrict__ bs,
    float* __restrict__ qbuf, float* __restrict__ kvbuf, float* __restrict__ sbuf,
    int n)
{
    int gid = blockIdx.x * 256 + threadIdx.x;
    if (gid >= n * 64) return;
    int i = gid >> 6, l = gid & 63;
    int j0 = 2 * l, j1 = 2 * l + 1;
    float x0 = x[2 * i], x1 = x[2 * i + 1];

    float q0 = fmaf(x1, Wq[HD + j0], fmaf(x0, Wq[j0], bq[j0]));
    float q1 = fmaf(x1, Wq[HD + j1], fmaf(x0, Wq[j1], bq[j1]));
    float k0 = fmaf(x1, Wk[HD + j0], fmaf(x0, Wk[j0], bk[j0]));
    float k1 = fmaf(x1, Wk[HD + j1], fmaf(x0, Wk[j1], bk[j1]));
    float v0 = fmaf(x1, Wv[HD + j0], fmaf(x0, Wv[j0], bv[j0]));
    float v1 = fmaf(x1, Wv[HD + j1], fmaf(x0, Wv[j1], bv[j1]));
    float s0 = fmaf(x1, Ws[HD + j0], fmaf(x0, Ws[j0], bs[j0]));
    float s1 = fmaf(x1, Ws[HD + j1], fmaf(x0, Ws[j1], bs[j1]));

    *(float2*)&qbuf[(size_t)i * HD + j0] = make_float2(q0, q1);
    *(float2*)&sbuf[(size_t)i * HD + j0] = make_float2(s0, s1);
    *(float4*)&kvbuf[(size_t)i * 256 + 4 * l] = make_float4(k0, k1, v0, v1);
}

// ---------------- CSR-by-dst build ----------------
__global__ __launch_bounds__(256) void hist_kernel(
    const int* __restrict__ dst, int* __restrict__ cnt, int E)
{
    int e = blockIdx.x * 256 + threadIdx.x;
    if (e < E) atomicAdd(&cnt[dst[e]], 1);
}

__global__ __launch_bounds__(1024) void scan_kernel(
    const int* __restrict__ cnt, int* __restrict__ row_ptr,
    int* __restrict__ cursor, int n)
{
    __shared__ int sdata[1024];
    int t = threadIdx.x;
    int CH = (n + 1023) >> 10;
    int lo = t * CH;
    int hi = lo + CH; if (hi > n) hi = n;
    int local = 0;
    for (int i = lo; i < hi; ++i) local += cnt[i];
    sdata[t] = local;
    __syncthreads();
    for (int off = 1; off < 1024; off <<= 1) {
        int val = (t >= off) ? sdata[t - off] : 0;
        __syncthreads();
        sdata[t] += val;
        __syncthreads();
    }
    int run = sdata[t] - local;
    for (int i = lo; i < hi; ++i) {
        row_ptr[i] = run; cursor[i] = run;
        run += cnt[i];
    }
    if (t == 1023) row_ptr[n] = run;
}

__global__ __launch_bounds__(256) void scatter_kernel(
    const int* __restrict__ dst, int* __restrict__ cursor,
    int* __restrict__ edge_ids, int E)
{
    int e = blockIdx.x * 256 + threadIdx.x;
    if (e < E) {
        int pos = atomicAdd(&cursor[dst[e]], 1);
        edge_ids[pos] = e;
    }
}

// ---------------- attention: one wave per node; one float4 kv gather per edge ----
__global__ __launch_bounds__(256) void attn_kernel(
    const float* __restrict__ qbuf, const float* __restrict__ kvbuf,
    const float* __restrict__ sbuf, const float* __restrict__ We,
    const float* __restrict__ eattr, const int* __restrict__ src,
    const int* __restrict__ row_ptr, const int* __restrict__ edge_ids,
    float* __restrict__ out, int n)
{
    int i = blockIdx.x * 4 + (threadIdx.x >> 6);
    if (i >= n) return;
    int l = threadIdx.x & 63;
    const float4* kvb = (const float4*)kvbuf;
    float2 q  = *(const float2*)&qbuf[(size_t)i * HD + 2 * l];
    float2 we = *(const float2*)&We[2 * l];
    int p0 = row_ptr[i], p1 = row_ptr[i + 1];
    float m = -INFINITY, s = 0.f;
    float2 acc = make_float2(0.f, 0.f);
    for (int p = p0; p < p1; ++p) {
        int e   = edge_ids[p];
        int sn  = src[e];
        float eav = eattr[e];
        float4 kv = kvb[(size_t)sn * 64 + l];
        float kx = fmaf(eav, we.x, kv.x), ky = fmaf(eav, we.y, kv.y);
        float vx = fmaf(eav, we.x, kv.z), vy = fmaf(eav, we.y, kv.w);
        float prod = fmaf(q.x, kx, q.y * ky);
        #pragma unroll
        for (int o = 16; o > 0; o >>= 1) prod += __shfl_xor(prod, o, 64);  // per-head (32-lane) reduce
        float logit = prod * 0.125f;          // / sqrt(64)
        float nm = fmaxf(m, logit);
        float sc = __expf(m - nm);            // first iter: exp(-inf)=0
        float ex = __expf(logit - nm);
        s     = fmaf(s, sc, ex);
        acc.x = fmaf(acc.x, sc, ex * vx);
        acc.y = fmaf(acc.y, sc, ex * vy);
        m = nm;
    }
    float inv = 1.f / (s + 1e-16f);
    float2 skp = *(const float2*)&sbuf[(size_t)i * HD + 2 * l];
    float2 res;
    res.x = fmaxf(fmaf(acc.x, inv, skp.x), 0.f);
    res.y = fmaxf(fmaf(acc.y, inv, skp.y), 0.f);
    *(float2*)&out[(size_t)i * HD + 2 * l] = res;
}

// ---------------- W pre-pack: f32 [128,128]x4 -> mfma B-fragment order, bf16 hi/lo ----
// Fragment index: [gnt(32)][ks(4)][lane(64)][j(8)]; value = Wcat[k = ks*32+(lane>>4)*8+j]
// [ncol = gnt*16+(lane&15)], Wcat = concat(q,k,v,s) along cols.
__global__ __launch_bounds__(256) void pack_kernel(
    const float* __restrict__ Wq, const float* __restrict__ Wk,
    const float* __restrict__ Wv, const float* __restrict__ Ws,
    const float* __restrict__ bq, const float* __restrict__ bk,
    const float* __restrict__ bv, const float* __restrict__ bs,
    unsigned short* __restrict__ Wph, unsigned short* __restrict__ Wpl,
    float* __restrict__ bias_cat)
{
    int id = blockIdx.x * 256 + threadIdx.x;   // 65536 fragment entries
    if (id < 65536) {
        int j = id & 7, lane = (id >> 3) & 63, ks = (id >> 9) & 3, gnt = id >> 11;
        int k = ks * 32 + (lane >> 4) * 8 + j;
        int ncol = gnt * 16 + (lane & 15);
        int mat = ncol >> 7, d = ncol & 127;
        const float* W = (mat == 0) ? Wq : (mat == 1) ? Wk : (mat == 2) ? Wv : Ws;
        float w = W[k * HD + d];
        unsigned short hi = f2bf(w);
        Wph[id] = hi;
        Wpl[id] = f2bf(w - bf2f(hi));
    }
    if (id < 512) {
        int mat = id >> 7, d = id & 127;
        const float* b = (mat == 0) ? bq : (mat == 1) ? bk : (mat == 2) ? bv : bs;
        bias_cat[id] = b[d];
    }
}

// ---------------- layer-1 linears: [n,128] @ [128,512] via split-bf16 MFMA --------
// Block: 64 rows x 256 cols (grid.y picks col half). 4 waves; wave w = rows w*16..w*16+15,
// loops 16 n-tiles of 16 cols. 3 mfma per K-step (ah*bh + ah*bl + al*bh), K=128 = 4 steps.
__global__ __launch_bounds__(256) void lin1_mfma(
    const float* __restrict__ A,
    const unsigned short* __restrict__ Wph, const unsigned short* __restrict__ Wpl,
    const float* __restrict__ bias_cat,
    float* __restrict__ qbuf, float* __restrict__ kvbuf, float* __restrict__ sbuf,
    int n)
{
    __shared__ float As[64 * 132];   // 33 KB, rows padded 128->132 to break LDS banks
    int tid = threadIdx.x;
    int row0 = blockIdx.x * 64;

    #pragma unroll
    for (int it = 0; it < 8; ++it) {
        int idx = it * 1024 + tid * 4;
        int r = idx >> 7, c = idx & 127;
        float4 av = make_float4(0.f, 0.f, 0.f, 0.f);
        if (row0 + r < n) av = *(const float4*)&A[(size_t)(row0 + r) * HD + c];
        *(float4*)&As[r * 132 + c] = av;
    }
    __syncthreads();

    int wave = tid >> 6, lane = tid & 63;
    int m = lane & 15, quad = lane >> 4;

    // A fragments for this wave's 16 rows, all 4 K-steps, hi/lo
    bf16x8 ah[4], al[4];
    const float* Arow = &As[(wave * 16 + m) * 132];
    #pragma unroll
    for (int ks = 0; ks < 4; ++ks) {
        float4 x0 = *(const float4*)&Arow[ks * 32 + quad * 8];
        float4 x1 = *(const float4*)&Arow[ks * 32 + quad * 8 + 4];
        float v[8] = {x0.x, x0.y, x0.z, x0.w, x1.x, x1.y, x1.z, x1.w};
        #pragma unroll
        for (int j = 0; j < 8; ++j) {
            unsigned short hi = f2bf(v[j]);
            ah[ks][j] = (short)hi;
            al[ks][j] = (short)f2bf(v[j] - bf2f(hi));
        }
    }

    const bf16x8* PH = (const bf16x8*)Wph;
    const bf16x8* PL = (const bf16x8*)Wpl;

    for (int nt = 0; nt < 16; ++nt) {
        int gnt = blockIdx.y * 16 + nt;
        f32x4 acc = {0.f, 0.f, 0.f, 0.f};
        #pragma unroll
        for (int ks = 0; ks < 4; ++ks) {
            bf16x8 bh = PH[(gnt * 4 + ks) * 64 + lane];
            bf16x8 bl = PL[(gnt * 4 + ks) * 64 + lane];
            acc = __builtin_amdgcn_mfma_f32_16x16x32_bf16(ah[ks], bh, acc, 0, 0, 0);
            acc = __builtin_amdgcn_mfma_f32_16x16x32_bf16(ah[ks], bl, acc, 0, 0, 0);
            acc = __builtin_amdgcn_mfma_f32_16x16x32_bf16(al[ks], bh, acc, 0, 0, 0);
        }
        // C/D: col = lane&15, row = quad*4 + reg  [m89-verified]
        int ocol = gnt * 16 + m;
        int mat = ocol >> 7, d = ocol & 127;
        float bias = bias_cat[ocol];
        #pragma unroll
        for (int reg = 0; reg < 4; ++reg) {
            int orow = row0 + wave * 16 + quad * 4 + reg;
            if (orow < n) {
                float val = acc[reg] + bias;
                if (mat == 0)      qbuf[(size_t)orow * HD + d] = val;
                else if (mat == 1) kvbuf[(size_t)orow * 256 + (d >> 1) * 4 + (d & 1)] = val;
                else if (mat == 2) kvbuf[(size_t)orow * 256 + (d >> 1) * 4 + 2 + (d & 1)] = val;
                else               sbuf[(size_t)orow * HD + d] = val;
            }
        }
    }
}

// ---------------- mean-pool (batch sorted -> run-length partials) ----------------
__global__ __launch_bounds__(128) void pool_kernel(
    const float* __restrict__ h, const int* __restrict__ batch,
    float* __restrict__ gsums, float* __restrict__ gcnt, int n)
{
    __shared__ int sb[64];
    int i0 = blockIdx.x * 64;
    int d = threadIdx.x;
    int iend = i0 + 64; if (iend > n) iend = n;
    int csize = iend - i0;
    if (d < csize) sb[d] = batch[i0 + d];
    __syncthreads();
    if (csize <= 0) return;
    float local = 0.f;
    int cur = sb[0];
    int runc = 0;
    for (int i = i0; i < iend; ++i) {
        int g = sb[i - i0];
        if (g != cur) {
            atomicAdd(&gsums[(size_t)cur * HD + d], local);
            if (d == 0) atomicAdd(&gcnt[cur], (float)runc);
            local = 0.f; runc = 0; cur = g;
        }
        local += h[(size_t)i * HD + d];
        runc++;
    }
    atomicAdd(&gsums[(size_t)cur * HD + d], local);
    if (d == 0) atomicAdd(&gcnt[cur], (float)runc);
}

// ---------------- classifier head: one block per graph ----------------
__global__ __launch_bounds__(128) void cls_kernel(
    const float* __restrict__ gsums, const float* __restrict__ gcnt,
    const float* __restrict__ cW1, const float* __restrict__ cb1,
    const float* __restrict__ cW2, const float* __restrict__ cb2,
    float* __restrict__ out)
{
    __shared__ float g[128];
    __shared__ float t[128];
    int gi = blockIdx.x, j = threadIdx.x;
    float c = fmaxf(gcnt[gi], 1.0f);
    g[j] = gsums[(size_t)gi * HD + j] / c;
    __syncthreads();
    float a = cb1[j];
    for (int k = 0; k < 128; ++k) a = fmaf(g[k], cW1[k * 128 + j], a);
    t[j] = fmaxf(a, 0.f);
    __syncthreads();
    if (j < 30) {
        float a2 = cb2[j];
        for (int k = 0; k < 128; ++k) a2 = fmaf(t[k], cW2[k * 30 + j], a2);
        out[gi * 30 + j] = a2;
    }
}

extern "C" void kernel_launch(void* const* d_in, const int* in_sizes, int n_in,
                              void* d_out, int out_size, void* d_ws, size_t ws_size,
                              hipStream_t stream)
{
    const float* x     = (const float*)d_in[0];
    const int*   ei    = (const int*)d_in[1];
    const float* eattr = (const float*)d_in[2];
    const int*   batch = (const int*)d_in[3];
    const float* l0_Wq = (const float*)d_in[4];
    const float* l0_bq = (const float*)d_in[5];
    const float* l0_Wk = (const float*)d_in[6];
    const float* l0_bk = (const float*)d_in[7];
    const float* l0_Wv = (const float*)d_in[8];
    const float* l0_bv = (const float*)d_in[9];
    const float* l0_We = (const float*)d_in[10];
    const float* l0_Ws = (const float*)d_in[11];
    const float* l0_bs = (const float*)d_in[12];
    const float* l1_Wq = (const float*)d_in[13];
    const float* l1_bq = (const float*)d_in[14];
    const float* l1_Wk = (const float*)d_in[15];
    const float* l1_bk = (const float*)d_in[16];
    const float* l1_Wv = (const float*)d_in[17];
    const float* l1_bv = (const float*)d_in[18];
    const float* l1_We = (const float*)d_in[19];
    const float* l1_Ws = (const float*)d_in[20];
    const float* l1_bs = (const float*)d_in[21];
    const float* cW1   = (const float*)d_in[22];
    const float* cb1   = (const float*)d_in[23];
    const float* cW2   = (const float*)d_in[24];
    const float* cb2   = (const float*)d_in[25];

    int n = in_sizes[0] / 2;     // 50000
    int E = in_sizes[2];         // 800000
    int G = out_size / 30;       // 64

    size_t nd = (size_t)n * HD;
    float* qbuf   = (float*)d_ws;                 // n*128
    float* kvbuf  = qbuf + nd;                    // n*256 (k/v interleaved per pair)
    float* sbuf   = kvbuf + 2 * nd;               // n*128
    float* h      = sbuf + nd;                    // n*128
    float* bias_cat = h + nd;                     // 512
    unsigned short* Wph = (unsigned short*)(bias_cat + 512);   // 65536
    unsigned short* Wpl = Wph + 65536;                         // 65536
    int* cnt      = (int*)(Wpl + 65536);          // n
    int* row_ptr  = cnt + n;                      // n+1
    int* cursor   = row_ptr + n + 1;              // n
    int* edge_ids = cursor + n;                   // E
    float* gsums  = (float*)(edge_ids + E);       // G*128
    float* gcnt   = gsums + (size_t)G * HD;       // G

    const int* srcI = ei;
    const int* dstI = ei + E;

    hipMemsetAsync(cnt, 0, (size_t)n * sizeof(int), stream);
    hipMemsetAsync(gsums, 0, ((size_t)G * HD + G) * sizeof(float), stream);

    hist_kernel<<<(E + 255) / 256, 256, 0, stream>>>(dstI, cnt, E);
    scan_kernel<<<1, 1024, 0, stream>>>(cnt, row_ptr, cursor, n);
    scatter_kernel<<<(E + 255) / 256, 256, 0, stream>>>(dstI, cursor, edge_ids, E);

    pack_kernel<<<256, 256, 0, stream>>>(l1_Wq, l1_Wk, l1_Wv, l1_Ws,
                                         l1_bq, l1_bk, l1_bv, l1_bs,
                                         Wph, Wpl, bias_cat);

    lin0_kernel<<<(n * 64 + 255) / 256, 256, 0, stream>>>(
        x, l0_Wq, l0_bq, l0_Wk, l0_bk, l0_Wv, l0_bv, l0_Ws, l0_bs,
        qbuf, kvbuf, sbuf, n);
    attn_kernel<<<(n + 3) / 4, 256, 0, stream>>>(
        qbuf, kvbuf, sbuf, l0_We, eattr, srcI, row_ptr, edge_ids, h, n);

    lin1_mfma<<<dim3((n + 63) / 64, 2), 256, 0, stream>>>(
        h, Wph, Wpl, bias_cat, qbuf, kvbuf, sbuf, n);
    attn_kernel<<<(n + 3) / 4, 256, 0, stream>>>(
        qbuf, kvbuf, sbuf, l1_We, eattr, srcI, row_ptr, edge_ids, h, n);

    pool_kernel<<<(n + 63) / 64, 128, 0, stream>>>(h, batch, gsums, gcnt, n);
    cls_kernel<<<G, 128, 0, stream>>>(gsums, gcnt, cW1, cb1, cW2, cb2, (float*)d_out);
}

// Round 3
// 656.317 us; speedup vs baseline: 1.2248x; 1.1528x over previous
//
#include <hip/hip_runtime.h>
#include <cstdint>
#include <cstddef>

#define HD 128

typedef short bf16x8 __attribute__((ext_vector_type(8)));   // 8 bf16 in 4 VGPRs
typedef float f32x4 __attribute__((ext_vector_type(4)));

__device__ __forceinline__ unsigned short f2bf(float f) {
    unsigned int u = __float_as_uint(f);
    u += 0x7fff + ((u >> 16) & 1);          // round-to-nearest-even
    return (unsigned short)(u >> 16);
}
__device__ __forceinline__ float bf2f(unsigned short h) {
    return __uint_as_float(((unsigned int)h) << 16);
}

// DPP butterfly add (VALU pipe, ~4cyc; vs ds_swizzle ~120cyc latency)
template<int CTRL>
__device__ __forceinline__ float dpp_add(float x) {
    int y = __builtin_amdgcn_update_dpp(0, __float_as_int(x), CTRL, 0xF, 0xF, true);
    return x + __int_as_float(y);
}
// sum over each 32-lane half (per attention head), result in all lanes of the half
__device__ __forceinline__ float half_reduce(float x) {
    x = dpp_add<0xB1>(x);    // quad_perm [1,0,3,2] : xor1
    x = dpp_add<0x4E>(x);    // quad_perm [2,3,0,1] : xor2
    x = dpp_add<0x124>(x);   // row_ror:4  -> each lane: sum of 2 adjacent quads
    x = dpp_add<0x128>(x);   // row_ror:8  -> row(16) sum in all 16 lanes
    x += __shfl_xor(x, 16, 64);  // combine the two rows of each 32-half
    return x;
}

// ---------------- layer-0 linears (fan-in = 2); writes q, interleaved kv, skip ----
// kv layout per node row (256 f32): lane l owns float4 (k_{2l},k_{2l+1},v_{2l},v_{2l+1})
__global__ __launch_bounds__(256) void lin0_kernel(
    const float* __restrict__ x,
    const float* __restrict__ Wq, const float* __restrict__ bq,
    const float* __restrict__ Wk, const float* __restrict__ bk,
    const float* __restrict__ Wv, const float* __restrict__ bv,
    const float* __restrict__ Ws, const float* __restrict__ bs,
    float* __restrict__ qbuf, float* __restrict__ kvbuf, float* __restrict__ sbuf,
    int n)
{
    int gid = blockIdx.x * 256 + threadIdx.x;
    if (gid >= n * 64) return;
    int i = gid >> 6, l = gid & 63;
    int j0 = 2 * l, j1 = 2 * l + 1;
    float x0 = x[2 * i], x1 = x[2 * i + 1];

    float q0 = fmaf(x1, Wq[HD + j0], fmaf(x0, Wq[j0], bq[j0]));
    float q1 = fmaf(x1, Wq[HD + j1], fmaf(x0, Wq[j1], bq[j1]));
    float k0 = fmaf(x1, Wk[HD + j0], fmaf(x0, Wk[j0], bk[j0]));
    float k1 = fmaf(x1, Wk[HD + j1], fmaf(x0, Wk[j1], bk[j1]));
    float v0 = fmaf(x1, Wv[HD + j0], fmaf(x0, Wv[j0], bv[j0]));
    float v1 = fmaf(x1, Wv[HD + j1], fmaf(x0, Wv[j1], bv[j1]));
    float s0 = fmaf(x1, Ws[HD + j0], fmaf(x0, Ws[j0], bs[j0]));
    float s1 = fmaf(x1, Ws[HD + j1], fmaf(x0, Ws[j1], bs[j1]));

    *(float2*)&qbuf[(size_t)i * HD + j0] = make_float2(q0, q1);
    *(float2*)&sbuf[(size_t)i * HD + j0] = make_float2(s0, s1);
    *(float4*)&kvbuf[(size_t)i * 256 + 4 * l] = make_float4(k0, k1, v0, v1);
}

// ---------------- CSR-by-dst build ----------------
__global__ __launch_bounds__(256) void hist_kernel(
    const int* __restrict__ dst, int* __restrict__ cnt, int E)
{
    int e = blockIdx.x * 256 + threadIdx.x;
    if (e < E) atomicAdd(&cnt[dst[e]], 1);
}

__global__ __launch_bounds__(1024) void scan_kernel(
    const int* __restrict__ cnt, int* __restrict__ row_ptr,
    int* __restrict__ cursor, int n)
{
    __shared__ int sdata[1024];
    int t = threadIdx.x;
    int CH = (n + 1023) >> 10;
    int lo = t * CH;
    int hi = lo + CH; if (hi > n) hi = n;
    int local = 0;
    for (int i = lo; i < hi; ++i) local += cnt[i];
    sdata[t] = local;
    __syncthreads();
    for (int off = 1; off < 1024; off <<= 1) {
        int val = (t >= off) ? sdata[t - off] : 0;
        __syncthreads();
        sdata[t] += val;
        __syncthreads();
    }
    int run = sdata[t] - local;
    for (int i = lo; i < hi; ++i) {
        row_ptr[i] = run; cursor[i] = run;
        run += cnt[i];
    }
    if (t == 1023) row_ptr[n] = run;
}

// scatter edges into CSR order; pack (src, eattr) so attn does ONE 8B load per edge
__global__ __launch_bounds__(256) void scatter_kernel(
    const int* __restrict__ dst, const int* __restrict__ src,
    const float* __restrict__ eattr, int* __restrict__ cursor,
    int2* __restrict__ epack, int E)
{
    int e = blockIdx.x * 256 + threadIdx.x;
    if (e < E) {
        int pos = atomicAdd(&cursor[dst[e]], 1);
        epack[pos] = make_int2(src[e], __float_as_int(eattr[e]));
    }
}

// ---------------- attention: one wave per node; 2-edge pipelined, DPP reduce ----
__global__ __launch_bounds__(256) void attn_kernel(
    const float* __restrict__ qbuf, const float* __restrict__ kvbuf,
    const float* __restrict__ sbuf, const float* __restrict__ We,
    const int2* __restrict__ epack, const int* __restrict__ row_ptr,
    float* __restrict__ out, int n)
{
    int i = blockIdx.x * 4 + (threadIdx.x >> 6);
    if (i >= n) return;
    int l = threadIdx.x & 63;
    const float4* kvb = (const float4*)kvbuf;
    float2 q  = *(const float2*)&qbuf[(size_t)i * HD + 2 * l];
    float2 we = *(const float2*)&We[2 * l];
    int p0 = __builtin_amdgcn_readfirstlane(row_ptr[i]);
    int p1 = __builtin_amdgcn_readfirstlane(row_ptr[i + 1]);

    float m = -INFINITY, s = 0.f;
    float2 acc = make_float2(0.f, 0.f);

    float4 kvA = {}, kvB = {};
    float eaA = 0.f, eaB = 0.f;
    int p = p0;
    if (p < p1) {
        int2 ep = epack[p];
        eaA = __int_as_float(ep.y);
        kvA = kvb[(size_t)ep.x * 64 + l];
    }
    if (p + 1 < p1) {
        int2 ep = epack[p + 1];
        eaB = __int_as_float(ep.y);
        kvB = kvb[(size_t)ep.x * 64 + l];
    }

    for (; p + 1 < p1; p += 2) {
        float4 cA = kvA; float aA = eaA;
        float4 cB = kvB; float aB = eaB;
        if (p + 2 < p1) {
            int2 ep = epack[p + 2];
            eaA = __int_as_float(ep.y);
            kvA = kvb[(size_t)ep.x * 64 + l];
        }
        if (p + 3 < p1) {
            int2 ep = epack[p + 3];
            eaB = __int_as_float(ep.y);
            kvB = kvb[(size_t)ep.x * 64 + l];
        }
        float kAx = fmaf(aA, we.x, cA.x), kAy = fmaf(aA, we.y, cA.y);
        float vAx = fmaf(aA, we.x, cA.z), vAy = fmaf(aA, we.y, cA.w);
        float kBx = fmaf(aB, we.x, cB.x), kBy = fmaf(aB, we.y, cB.y);
        float vBx = fmaf(aB, we.x, cB.z), vBy = fmaf(aB, we.y, cB.w);
        float lA = half_reduce(fmaf(q.x, kAx, q.y * kAy)) * 0.125f;
        float lB = half_reduce(fmaf(q.x, kBx, q.y * kBy)) * 0.125f;
        // fused dual online-softmax update (3 exps / 2 edges)
        float nm = fmaxf(fmaxf(m, lA), lB);
        float sc = __expf(m - nm);
        float eA = __expf(lA - nm);
        float eB = __expf(lB - nm);
        s     = fmaf(s, sc, eA + eB);
        acc.x = fmaf(acc.x, sc, fmaf(eA, vAx, eB * vBx));
        acc.y = fmaf(acc.y, sc, fmaf(eA, vAy, eB * vBy));
        m = nm;
    }
    if (p < p1) {
        float kx = fmaf(eaA, we.x, kvA.x), ky = fmaf(eaA, we.y, kvA.y);
        float vx = fmaf(eaA, we.x, kvA.z), vy = fmaf(eaA, we.y, kvA.w);
        float lg = half_reduce(fmaf(q.x, kx, q.y * ky)) * 0.125f;
        float nm = fmaxf(m, lg);
        float sc = __expf(m - nm);
        float ex = __expf(lg - nm);
        s     = fmaf(s, sc, ex);
        acc.x = fmaf(acc.x, sc, ex * vx);
        acc.y = fmaf(acc.y, sc, ex * vy);
    }
    float inv = 1.f / (s + 1e-16f);
    float2 skp = *(const float2*)&sbuf[(size_t)i * HD + 2 * l];
    float2 res;
    res.x = fmaxf(fmaf(acc.x, inv, skp.x), 0.f);
    res.y = fmaxf(fmaf(acc.y, inv, skp.y), 0.f);
    *(float2*)&out[(size_t)i * HD + 2 * l] = res;
}

// ---------------- W pre-pack: f32 [128,128]x4 -> mfma B-fragment order, bf16 hi/lo ----
__global__ __launch_bounds__(256) void pack_kernel(
    const float* __restrict__ Wq, const float* __restrict__ Wk,
    const float* __restrict__ Wv, const float* __restrict__ Ws,
    const float* __restrict__ bq, const float* __restrict__ bk,
    const float* __restrict__ bv, const float* __restrict__ bs,
    unsigned short* __restrict__ Wph, unsigned short* __restrict__ Wpl,
    float* __restrict__ bias_cat)
{
    int id = blockIdx.x * 256 + threadIdx.x;   // 65536 fragment entries
    if (id < 65536) {
        int j = id & 7, lane = (id >> 3) & 63, ks = (id >> 9) & 3, gnt = id >> 11;
        int k = ks * 32 + (lane >> 4) * 8 + j;
        int ncol = gnt * 16 + (lane & 15);
        int mat = ncol >> 7, d = ncol & 127;
        const float* W = (mat == 0) ? Wq : (mat == 1) ? Wk : (mat == 2) ? Wv : Ws;
        float w = W[k * HD + d];
        unsigned short hi = f2bf(w);
        Wph[id] = hi;
        Wpl[id] = f2bf(w - bf2f(hi));
    }
    if (id < 512) {
        int mat = id >> 7, d = id & 127;
        const float* b = (mat == 0) ? bq : (mat == 1) ? bk : (mat == 2) ? bv : bs;
        bias_cat[id] = b[d];
    }
}

// ---------------- layer-1 linears: [n,128] @ [128,512] via split-bf16 MFMA --------
__global__ __launch_bounds__(256) void lin1_mfma(
    const float* __restrict__ A,
    const unsigned short* __restrict__ Wph, const unsigned short* __restrict__ Wpl,
    const float* __restrict__ bias_cat,
    float* __restrict__ qbuf, float* __restrict__ kvbuf, float* __restrict__ sbuf,
    int n)
{
    __shared__ float As[64 * 132];   // 33 KB, rows padded 128->132 to break LDS banks
    int tid = threadIdx.x;
    int row0 = blockIdx.x * 64;

    #pragma unroll
    for (int it = 0; it < 8; ++it) {
        int idx = it * 1024 + tid * 4;
        int r = idx >> 7, c = idx & 127;
        float4 av = make_float4(0.f, 0.f, 0.f, 0.f);
        if (row0 + r < n) av = *(const float4*)&A[(size_t)(row0 + r) * HD + c];
        *(float4*)&As[r * 132 + c] = av;
    }
    __syncthreads();

    int wave = tid >> 6, lane = tid & 63;
    int m = lane & 15, quad = lane >> 4;

    bf16x8 ah[4], al[4];
    const float* Arow = &As[(wave * 16 + m) * 132];
    #pragma unroll
    for (int ks = 0; ks < 4; ++ks) {
        float4 x0 = *(const float4*)&Arow[ks * 32 + quad * 8];
        float4 x1 = *(const float4*)&Arow[ks * 32 + quad * 8 + 4];
        float v[8] = {x0.x, x0.y, x0.z, x0.w, x1.x, x1.y, x1.z, x1.w};
        #pragma unroll
        for (int j = 0; j < 8; ++j) {
            unsigned short hi = f2bf(v[j]);
            ah[ks][j] = (short)hi;
            al[ks][j] = (short)f2bf(v[j] - bf2f(hi));
        }
    }

    const bf16x8* PH = (const bf16x8*)Wph;
    const bf16x8* PL = (const bf16x8*)Wpl;

    for (int nt = 0; nt < 16; ++nt) {
        int gnt = blockIdx.y * 16 + nt;
        f32x4 acc = {0.f, 0.f, 0.f, 0.f};
        #pragma unroll
        for (int ks = 0; ks < 4; ++ks) {
            bf16x8 bh = PH[(gnt * 4 + ks) * 64 + lane];
            bf16x8 bl = PL[(gnt * 4 + ks) * 64 + lane];
            acc = __builtin_amdgcn_mfma_f32_16x16x32_bf16(ah[ks], bh, acc, 0, 0, 0);
            acc = __builtin_amdgcn_mfma_f32_16x16x32_bf16(ah[ks], bl, acc, 0, 0, 0);
            acc = __builtin_amdgcn_mfma_f32_16x16x32_bf16(al[ks], bh, acc, 0, 0, 0);
        }
        int ocol = gnt * 16 + m;
        int mat = ocol >> 7, d = ocol & 127;
        float bias = bias_cat[ocol];
        #pragma unroll
        for (int reg = 0; reg < 4; ++reg) {
            int orow = row0 + wave * 16 + quad * 4 + reg;
            if (orow < n) {
                float val = acc[reg] + bias;
                if (mat == 0)      qbuf[(size_t)orow * HD + d] = val;
                else if (mat == 1) kvbuf[(size_t)orow * 256 + (d >> 1) * 4 + (d & 1)] = val;
                else if (mat == 2) kvbuf[(size_t)orow * 256 + (d >> 1) * 4 + 2 + (d & 1)] = val;
                else               sbuf[(size_t)orow * HD + d] = val;
            }
        }
    }
}

// ---------------- mean-pool (batch sorted -> run-length partials) ----------------
__global__ __launch_bounds__(128) void pool_kernel(
    const float* __restrict__ h, const int* __restrict__ batch,
    float* __restrict__ gsums, float* __restrict__ gcnt, int n)
{
    __shared__ int sb[64];
    int i0 = blockIdx.x * 64;
    int d = threadIdx.x;
    int iend = i0 + 64; if (iend > n) iend = n;
    int csize = iend - i0;
    if (d < csize) sb[d] = batch[i0 + d];
    __syncthreads();
    if (csize <= 0) return;
    float local = 0.f;
    int cur = sb[0];
    int runc = 0;
    for (int i = i0; i < iend; ++i) {
        int g = sb[i - i0];
        if (g != cur) {
            atomicAdd(&gsums[(size_t)cur * HD + d], local);
            if (d == 0) atomicAdd(&gcnt[cur], (float)runc);
            local = 0.f; runc = 0; cur = g;
        }
        local += h[(size_t)i * HD + d];
        runc++;
    }
    atomicAdd(&gsums[(size_t)cur * HD + d], local);
    if (d == 0) atomicAdd(&gcnt[cur], (float)runc);
}

// ---------------- classifier head: one block per graph ----------------
__global__ __launch_bounds__(128) void cls_kernel(
    const float* __restrict__ gsums, const float* __restrict__ gcnt,
    const float* __restrict__ cW1, const float* __restrict__ cb1,
    const float* __restrict__ cW2, const float* __restrict__ cb2,
    float* __restrict__ out)
{
    __shared__ float g[128];
    __shared__ float t[128];
    int gi = blockIdx.x, j = threadIdx.x;
    float c = fmaxf(gcnt[gi], 1.0f);
    g[j] = gsums[(size_t)gi * HD + j] / c;
    __syncthreads();
    float a = cb1[j];
    for (int k = 0; k < 128; ++k) a = fmaf(g[k], cW1[k * 128 + j], a);
    t[j] = fmaxf(a, 0.f);
    __syncthreads();
    if (j < 30) {
        float a2 = cb2[j];
        for (int k = 0; k < 128; ++k) a2 = fmaf(t[k], cW2[k * 30 + j], a2);
        out[gi * 30 + j] = a2;
    }
}

extern "C" void kernel_launch(void* const* d_in, const int* in_sizes, int n_in,
                              void* d_out, int out_size, void* d_ws, size_t ws_size,
                              hipStream_t stream)
{
    const float* x     = (const float*)d_in[0];
    const int*   ei    = (const int*)d_in[1];
    const float* eattr = (const float*)d_in[2];
    const int*   batch = (const int*)d_in[3];
    const float* l0_Wq = (const float*)d_in[4];
    const float* l0_bq = (const float*)d_in[5];
    const float* l0_Wk = (const float*)d_in[6];
    const float* l0_bk = (const float*)d_in[7];
    const float* l0_Wv = (const float*)d_in[8];
    const float* l0_bv = (const float*)d_in[9];
    const float* l0_We = (const float*)d_in[10];
    const float* l0_Ws = (const float*)d_in[11];
    const float* l0_bs = (const float*)d_in[12];
    const float* l1_Wq = (const float*)d_in[13];
    const float* l1_bq = (const float*)d_in[14];
    const float* l1_Wk = (const float*)d_in[15];
    const float* l1_bk = (const float*)d_in[16];
    const float* l1_Wv = (const float*)d_in[17];
    const float* l1_bv = (const float*)d_in[18];
    const float* l1_We = (const float*)d_in[19];
    const float* l1_Ws = (const float*)d_in[20];
    const float* l1_bs = (const float*)d_in[21];
    const float* cW1   = (const float*)d_in[22];
    const float* cb1   = (const float*)d_in[23];
    const float* cW2   = (const float*)d_in[24];
    const float* cb2   = (const float*)d_in[25];

    int n = in_sizes[0] / 2;     // 50000
    int E = in_sizes[2];         // 800000
    int G = out_size / 30;       // 64

    size_t nd = (size_t)n * HD;
    float* qbuf   = (float*)d_ws;                 // n*128
    float* kvbuf  = qbuf + nd;                    // n*256 (k/v interleaved per pair)
    float* sbuf   = kvbuf + 2 * nd;               // n*128
    float* h      = sbuf + nd;                    // n*128
    float* bias_cat = h + nd;                     // 512
    unsigned short* Wph = (unsigned short*)(bias_cat + 512);   // 65536
    unsigned short* Wpl = Wph + 65536;                         // 65536
    int2* epack   = (int2*)(Wpl + 65536);         // E (8B each, 8-aligned here)
    int* cnt      = (int*)(epack + E);            // n
    int* row_ptr  = cnt + n;                      // n+1
    int* cursor   = row_ptr + n + 1;              // n
    float* gsums  = (float*)(cursor + n);         // G*128
    float* gcnt   = gsums + (size_t)G * HD;       // G

    const int* srcI = ei;
    const int* dstI = ei + E;

    hipMemsetAsync(cnt, 0, (size_t)n * sizeof(int), stream);
    hipMemsetAsync(gsums, 0, ((size_t)G * HD + G) * sizeof(float), stream);

    hist_kernel<<<(E + 255) / 256, 256, 0, stream>>>(dstI, cnt, E);
    scan_kernel<<<1, 1024, 0, stream>>>(cnt, row_ptr, cursor, n);
    scatter_kernel<<<(E + 255) / 256, 256, 0, stream>>>(dstI, srcI, eattr, cursor, epack, E);

    pack_kernel<<<256, 256, 0, stream>>>(l1_Wq, l1_Wk, l1_Wv, l1_Ws,
                                         l1_bq, l1_bk, l1_bv, l1_bs,
                                         Wph, Wpl, bias_cat);

    lin0_kernel<<<(n * 64 + 255) / 256, 256, 0, stream>>>(
        x, l0_Wq, l0_bq, l0_Wk, l0_bk, l0_Wv, l0_bv, l0_Ws, l0_bs,
        qbuf, kvbuf, sbuf, n);
    attn_kernel<<<(n + 3) / 4, 256, 0, stream>>>(
        qbuf, kvbuf, sbuf, l0_We, epack, row_ptr, h, n);

    lin1_mfma<<<dim3((n + 63) / 64, 2), 256, 0, stream>>>(
        h, Wph, Wpl, bias_cat, qbuf, kvbuf, sbuf, n);
    attn_kernel<<<(n + 3) / 4, 256, 0, stream>>>(
        qbuf, kvbuf, sbuf, l1_We, epack, row_ptr, h, n);

    pool_kernel<<<(n + 63) / 64, 128, 0, stream>>>(h, batch, gsums, gcnt, n);
    cls_kernel<<<G, 128, 0, stream>>>(gsums, gcnt, cW1, cb1, cW2, cb2, (float*)d_out);
}

// Round 4
// 566.571 us; speedup vs baseline: 1.4188x; 1.1584x over previous
//
#include <hip/hip_runtime.h>
#include <cstdint>
#include <cstddef>

#define HD 128

typedef short bf16x8 __attribute__((ext_vector_type(8)));   // 8 bf16 in 4 VGPRs
typedef float f32x4 __attribute__((ext_vector_type(4)));

__device__ __forceinline__ unsigned short f2bf(float f) {
    unsigned int u = __float_as_uint(f);
    u += 0x7fff + ((u >> 16) & 1);          // round-to-nearest-even
    return (unsigned short)(u >> 16);
}
__device__ __forceinline__ float bf2f(unsigned short h) {
    return __uint_as_float(((unsigned int)h) << 16);
}

// DPP butterfly add (VALU pipe) — reduce within each 32-lane half (per head)
template<int CTRL>
__device__ __forceinline__ float dpp_add(float x) {
    int y = __builtin_amdgcn_update_dpp(0, __float_as_int(x), CTRL, 0xF, 0xF, true);
    return x + __int_as_float(y);
}
__device__ __forceinline__ float half_reduce(float x) {
    x = dpp_add<0xB1>(x);    // quad_perm xor1
    x = dpp_add<0x4E>(x);    // quad_perm xor2
    x = dpp_add<0x124>(x);   // row_ror:4
    x = dpp_add<0x128>(x);   // row_ror:8 -> row(16) sums
    x += __shfl_xor(x, 16, 64);  // combine two rows of the 32-half
    return x;
}

// fused dual online-softmax update (3 exps / 2 edges)
__device__ __forceinline__ void pair_update(
    float& m, float& s, float2& acc, float2 q,
    float kAx, float kAy, float vAx, float vAy,
    float kBx, float kBy, float vBx, float vBy)
{
    float lA = half_reduce(fmaf(q.x, kAx, q.y * kAy)) * 0.125f;
    float lB = half_reduce(fmaf(q.x, kBx, q.y * kBy)) * 0.125f;
    float nm = fmaxf(fmaxf(m, lA), lB);
    float sc = __expf(m - nm);
    float eA = __expf(lA - nm);
    float eB = __expf(lB - nm);
    s     = fmaf(s, sc, eA + eB);
    acc.x = fmaf(acc.x, sc, fmaf(eA, vAx, eB * vBx));
    acc.y = fmaf(acc.y, sc, fmaf(eA, vAy, eB * vBy));
    m = nm;
}
__device__ __forceinline__ void single_update(
    float& m, float& s, float2& acc, float2 q,
    float kx, float ky, float vx, float vy)
{
    float lg = half_reduce(fmaf(q.x, kx, q.y * ky)) * 0.125f;
    float nm = fmaxf(m, lg);
    float sc = __expf(m - nm);
    float ex = __expf(lg - nm);
    s     = fmaf(s, sc, ex);
    acc.x = fmaf(acc.x, sc, ex * vx);
    acc.y = fmaf(acc.y, sc, ex * vy);
    m = nm;
}

// ---------------- CSR-by-dst build ----------------
__global__ __launch_bounds__(256) void hist_kernel(
    const int* __restrict__ dst, int* __restrict__ cnt, int E)
{
    int e = blockIdx.x * 256 + threadIdx.x;
    if (e < E) atomicAdd(&cnt[dst[e]], 1);
}

__global__ __launch_bounds__(1024) void scan_kernel(
    const int* __restrict__ cnt, int* __restrict__ row_ptr,
    int* __restrict__ cursor, int n)
{
    __shared__ int sdata[1024];
    int t = threadIdx.x;
    int CH = (n + 1023) >> 10;
    int lo = t * CH;
    int hi = lo + CH; if (hi > n) hi = n;
    int local = 0;
    for (int i = lo; i < hi; ++i) local += cnt[i];
    sdata[t] = local;
    __syncthreads();
    for (int off = 1; off < 1024; off <<= 1) {
        int val = (t >= off) ? sdata[t - off] : 0;
        __syncthreads();
        sdata[t] += val;
        __syncthreads();
    }
    int run = sdata[t] - local;
    for (int i = lo; i < hi; ++i) {
        row_ptr[i] = run; cursor[i] = run;
        run += cnt[i];
    }
    if (t == 1023) row_ptr[n] = run;
}

__global__ __launch_bounds__(256) void scatter_kernel(
    const int* __restrict__ dst, const int* __restrict__ src,
    const float* __restrict__ eattr, int* __restrict__ cursor,
    int2* __restrict__ epack, int E)
{
    int e = blockIdx.x * 256 + threadIdx.x;
    if (e < E) {
        int pos = atomicAdd(&cursor[dst[e]], 1);
        epack[pos] = make_int2(src[e], __float_as_int(eattr[e]));
    }
}

// ---------------- layer-0 attention, fully fused (fan-in=2 -> k,v on the fly) ----
// Per edge: 8B epack broadcast + 8B x[src] broadcast; no lin0, no kv gather.
__global__ __launch_bounds__(256) void attn0_kernel(
    const float* __restrict__ x,
    const float* __restrict__ Wq, const float* __restrict__ bq,
    const float* __restrict__ Wk, const float* __restrict__ bk,
    const float* __restrict__ Wv, const float* __restrict__ bv,
    const float* __restrict__ We, const float* __restrict__ Ws,
    const float* __restrict__ bs,
    const int2* __restrict__ epack, const int* __restrict__ row_ptr,
    float* __restrict__ out, int n)
{
    int i = blockIdx.x * 4 + (threadIdx.x >> 6);
    if (i >= n) return;
    int l = threadIdx.x & 63;
    int j0 = 2 * l;

    // per-lane weight columns (rows 0/1 of [2,128] mats)
    float2 wk0 = *(const float2*)&Wk[j0];
    float2 wk1 = *(const float2*)&Wk[HD + j0];
    float2 wv0 = *(const float2*)&Wv[j0];
    float2 wv1 = *(const float2*)&Wv[HD + j0];
    float2 bk2 = *(const float2*)&bk[j0];
    float2 bv2 = *(const float2*)&bv[j0];
    float2 we  = *(const float2*)&We[j0];

    // own q (and skip at the end)
    float x0 = x[2 * i], x1 = x[2 * i + 1];
    float2 wq0 = *(const float2*)&Wq[j0];
    float2 wq1 = *(const float2*)&Wq[HD + j0];
    float2 bq2 = *(const float2*)&bq[j0];
    float2 q;
    q.x = fmaf(x1, wq1.x, fmaf(x0, wq0.x, bq2.x));
    q.y = fmaf(x1, wq1.y, fmaf(x0, wq0.y, bq2.y));

    int p0 = __builtin_amdgcn_readfirstlane(row_ptr[i]);
    int p1 = __builtin_amdgcn_readfirstlane(row_ptr[i + 1]);

    float m = -INFINITY, s = 0.f;
    float2 acc = make_float2(0.f, 0.f);

    float2 xs0 = {}, xs1 = {}, xs2 = {}, xs3 = {};
    float ea0 = 0.f, ea1 = 0.f, ea2 = 0.f, ea3 = 0.f;

#define LD0(t, idx) do { if ((idx) < p1) { int2 ep_ = epack[idx]; \
    ea##t = __int_as_float(ep_.y); xs##t = *(const float2*)&x[2 * ep_.x]; } } while (0)

    LD0(0, p0); LD0(1, p0 + 1); LD0(2, p0 + 2); LD0(3, p0 + 3);

#define KV0(xs, ea, kx, ky, vx, vy) \
    float kx = fmaf(ea, we.x, fmaf(xs.y, wk1.x, fmaf(xs.x, wk0.x, bk2.x))); \
    float ky = fmaf(ea, we.y, fmaf(xs.y, wk1.y, fmaf(xs.x, wk0.y, bk2.y))); \
    float vx = fmaf(ea, we.x, fmaf(xs.y, wv1.x, fmaf(xs.x, wv0.x, bv2.x))); \
    float vy = fmaf(ea, we.y, fmaf(xs.y, wv1.y, fmaf(xs.x, wv0.y, bv2.y)));

    int p = p0;
    for (; p + 3 < p1; p += 4) {
        float2 c0 = xs0, c1 = xs1, c2 = xs2, c3 = xs3;
        float a0 = ea0, a1 = ea1, a2 = ea2, a3 = ea3;
        LD0(0, p + 4); LD0(1, p + 5); LD0(2, p + 6); LD0(3, p + 7);
        { KV0(c0, a0, kAx, kAy, vAx, vAy) KV0(c1, a1, kBx, kBy, vBx, vBy)
          pair_update(m, s, acc, q, kAx, kAy, vAx, vAy, kBx, kBy, vBx, vBy); }
        { KV0(c2, a2, kAx, kAy, vAx, vAy) KV0(c3, a3, kBx, kBy, vBx, vBy)
          pair_update(m, s, acc, q, kAx, kAy, vAx, vAy, kBx, kBy, vBx, vBy); }
    }
    int rem = p1 - p;
    if (rem >= 2) {
        KV0(xs0, ea0, kAx, kAy, vAx, vAy) KV0(xs1, ea1, kBx, kBy, vBx, vBy)
        pair_update(m, s, acc, q, kAx, kAy, vAx, vAy, kBx, kBy, vBx, vBy);
    }
    if (rem == 1) {
        KV0(xs0, ea0, kx, ky, vx, vy)
        single_update(m, s, acc, q, kx, ky, vx, vy);
    } else if (rem == 3) {
        KV0(xs2, ea2, kx, ky, vx, vy)
        single_update(m, s, acc, q, kx, ky, vx, vy);
    }

    float inv = 1.f / (s + 1e-16f);
    float2 ws0 = *(const float2*)&Ws[j0];
    float2 ws1 = *(const float2*)&Ws[HD + j0];
    float2 bs2 = *(const float2*)&bs[j0];
    float sk_x = fmaf(x1, ws1.x, fmaf(x0, ws0.x, bs2.x));
    float sk_y = fmaf(x1, ws1.y, fmaf(x0, ws0.y, bs2.y));
    float2 res;
    res.x = fmaxf(fmaf(acc.x, inv, sk_x), 0.f);
    res.y = fmaxf(fmaf(acc.y, inv, sk_y), 0.f);
    *(float2*)&out[(size_t)i * HD + j0] = res;
}

// ---------------- layer-1 attention: gather kv, depth-4 prefetch pipeline ----
__global__ __launch_bounds__(256) void attn_kernel(
    const float* __restrict__ qbuf, const float* __restrict__ kvbuf,
    const float* __restrict__ sbuf, const float* __restrict__ We,
    const int2* __restrict__ epack, const int* __restrict__ row_ptr,
    float* __restrict__ out, int n)
{
    int i = blockIdx.x * 4 + (threadIdx.x >> 6);
    if (i >= n) return;
    int l = threadIdx.x & 63;
    const float4* kvb = (const float4*)kvbuf;
    float2 q  = *(const float2*)&qbuf[(size_t)i * HD + 2 * l];
    float2 we = *(const float2*)&We[2 * l];
    int p0 = __builtin_amdgcn_readfirstlane(row_ptr[i]);
    int p1 = __builtin_amdgcn_readfirstlane(row_ptr[i + 1]);

    float m = -INFINITY, s = 0.f;
    float2 acc = make_float2(0.f, 0.f);

    float4 kv0 = {}, kv1 = {}, kv2 = {}, kv3 = {};
    float ea0 = 0.f, ea1 = 0.f, ea2 = 0.f, ea3 = 0.f;

#define LD1(t, idx) do { if ((idx) < p1) { int2 ep_ = epack[idx]; \
    ea##t = __int_as_float(ep_.y); kv##t = kvb[(size_t)ep_.x * 64 + l]; } } while (0)

    LD1(0, p0); LD1(1, p0 + 1); LD1(2, p0 + 2); LD1(3, p0 + 3);

    int p = p0;
    for (; p + 3 < p1; p += 4) {
        float4 c0 = kv0, c1 = kv1, c2 = kv2, c3 = kv3;
        float a0 = ea0, a1 = ea1, a2 = ea2, a3 = ea3;
        LD1(0, p + 4); LD1(1, p + 5); LD1(2, p + 6); LD1(3, p + 7);
        pair_update(m, s, acc, q,
            fmaf(a0, we.x, c0.x), fmaf(a0, we.y, c0.y),
            fmaf(a0, we.x, c0.z), fmaf(a0, we.y, c0.w),
            fmaf(a1, we.x, c1.x), fmaf(a1, we.y, c1.y),
            fmaf(a1, we.x, c1.z), fmaf(a1, we.y, c1.w));
        pair_update(m, s, acc, q,
            fmaf(a2, we.x, c2.x), fmaf(a2, we.y, c2.y),
            fmaf(a2, we.x, c2.z), fmaf(a2, we.y, c2.w),
            fmaf(a3, we.x, c3.x), fmaf(a3, we.y, c3.y),
            fmaf(a3, we.x, c3.z), fmaf(a3, we.y, c3.w));
    }
    int rem = p1 - p;
    if (rem >= 2) {
        pair_update(m, s, acc, q,
            fmaf(ea0, we.x, kv0.x), fmaf(ea0, we.y, kv0.y),
            fmaf(ea0, we.x, kv0.z), fmaf(ea0, we.y, kv0.w),
            fmaf(ea1, we.x, kv1.x), fmaf(ea1, we.y, kv1.y),
            fmaf(ea1, we.x, kv1.z), fmaf(ea1, we.y, kv1.w));
    }
    if (rem == 1) {
        single_update(m, s, acc, q,
            fmaf(ea0, we.x, kv0.x), fmaf(ea0, we.y, kv0.y),
            fmaf(ea0, we.x, kv0.z), fmaf(ea0, we.y, kv0.w));
    } else if (rem == 3) {
        single_update(m, s, acc, q,
            fmaf(ea2, we.x, kv2.x), fmaf(ea2, we.y, kv2.y),
            fmaf(ea2, we.x, kv2.z), fmaf(ea2, we.y, kv2.w));
    }

    float inv = 1.f / (s + 1e-16f);
    float2 skp = *(const float2*)&sbuf[(size_t)i * HD + 2 * l];
    float2 res;
    res.x = fmaxf(fmaf(acc.x, inv, skp.x), 0.f);
    res.y = fmaxf(fmaf(acc.y, inv, skp.y), 0.f);
    *(float2*)&out[(size_t)i * HD + 2 * l] = res;
}

// ---------------- W pre-pack: f32 [128,128]x4 -> mfma B-fragment order, bf16 hi/lo ----
__global__ __launch_bounds__(256) void pack_kernel(
    const float* __restrict__ Wq, const float* __restrict__ Wk,
    const float* __restrict__ Wv, const float* __restrict__ Ws,
    const float* __restrict__ bq, const float* __restrict__ bk,
    const float* __restrict__ bv, const float* __restrict__ bs,
    unsigned short* __restrict__ Wph, unsigned short* __restrict__ Wpl,
    float* __restrict__ bias_cat)
{
    int id = blockIdx.x * 256 + threadIdx.x;   // 65536 fragment entries
    if (id < 65536) {
        int j = id & 7, lane = (id >> 3) & 63, ks = (id >> 9) & 3, gnt = id >> 11;
        int k = ks * 32 + (lane >> 4) * 8 + j;
        int ncol = gnt * 16 + (lane & 15);
        int mat = ncol >> 7, d = ncol & 127;
        const float* W = (mat == 0) ? Wq : (mat == 1) ? Wk : (mat == 2) ? Wv : Ws;
        float w = W[k * HD + d];
        unsigned short hi = f2bf(w);
        Wph[id] = hi;
        Wpl[id] = f2bf(w - bf2f(hi));
    }
    if (id < 512) {
        int mat = id >> 7, d = id & 127;
        const float* b = (mat == 0) ? bq : (mat == 1) ? bk : (mat == 2) ? bv : bs;
        bias_cat[id] = b[d];
    }
}

// ---------------- layer-1 linears: [n,128] @ [128,512] via split-bf16 MFMA --------
__global__ __launch_bounds__(256) void lin1_mfma(
    const float* __restrict__ A,
    const unsigned short* __restrict__ Wph, const unsigned short* __restrict__ Wpl,
    const float* __restrict__ bias_cat,
    float* __restrict__ qbuf, float* __restrict__ kvbuf, float* __restrict__ sbuf,
    int n)
{
    __shared__ float As[64 * 132];   // 33 KB, rows padded 128->132
    int tid = threadIdx.x;
    int row0 = blockIdx.x * 64;

    #pragma unroll
    for (int it = 0; it < 8; ++it) {
        int idx = it * 1024 + tid * 4;
        int r = idx >> 7, c = idx & 127;
        float4 av = make_float4(0.f, 0.f, 0.f, 0.f);
        if (row0 + r < n) av = *(const float4*)&A[(size_t)(row0 + r) * HD + c];
        *(float4*)&As[r * 132 + c] = av;
    }
    __syncthreads();

    int wave = tid >> 6, lane = tid & 63;
    int m = lane & 15, quad = lane >> 4;

    bf16x8 ah[4], al[4];
    const float* Arow = &As[(wave * 16 + m) * 132];
    #pragma unroll
    for (int ks = 0; ks < 4; ++ks) {
        float4 x0 = *(const float4*)&Arow[ks * 32 + quad * 8];
        float4 x1 = *(const float4*)&Arow[ks * 32 + quad * 8 + 4];
        float v[8] = {x0.x, x0.y, x0.z, x0.w, x1.x, x1.y, x1.z, x1.w};
        #pragma unroll
        for (int j = 0; j < 8; ++j) {
            unsigned short hi = f2bf(v[j]);
            ah[ks][j] = (short)hi;
            al[ks][j] = (short)f2bf(v[j] - bf2f(hi));
        }
    }

    const bf16x8* PH = (const bf16x8*)Wph;
    const bf16x8* PL = (const bf16x8*)Wpl;

    for (int nt = 0; nt < 16; ++nt) {
        int gnt = blockIdx.y * 16 + nt;
        f32x4 acc = {0.f, 0.f, 0.f, 0.f};
        #pragma unroll
        for (int ks = 0; ks < 4; ++ks) {
            bf16x8 bh = PH[(gnt * 4 + ks) * 64 + lane];
            bf16x8 bl = PL[(gnt * 4 + ks) * 64 + lane];
            acc = __builtin_amdgcn_mfma_f32_16x16x32_bf16(ah[ks], bh, acc, 0, 0, 0);
            acc = __builtin_amdgcn_mfma_f32_16x16x32_bf16(ah[ks], bl, acc, 0, 0, 0);
            acc = __builtin_amdgcn_mfma_f32_16x16x32_bf16(al[ks], bh, acc, 0, 0, 0);
        }
        int ocol = gnt * 16 + m;
        int mat = ocol >> 7, d = ocol & 127;
        float bias = bias_cat[ocol];
        #pragma unroll
        for (int reg = 0; reg < 4; ++reg) {
            int orow = row0 + wave * 16 + quad * 4 + reg;
            if (orow < n) {
                float val = acc[reg] + bias;
                if (mat == 0)      qbuf[(size_t)orow * HD + d] = val;
                else if (mat == 1) kvbuf[(size_t)orow * 256 + (d >> 1) * 4 + (d & 1)] = val;
                else if (mat == 2) kvbuf[(size_t)orow * 256 + (d >> 1) * 4 + 2 + (d & 1)] = val;
                else               sbuf[(size_t)orow * HD + d] = val;
            }
        }
    }
}

// ---------------- mean-pool (batch sorted -> run-length partials) ----------------
__global__ __launch_bounds__(128) void pool_kernel(
    const float* __restrict__ h, const int* __restrict__ batch,
    float* __restrict__ gsums, float* __restrict__ gcnt, int n)
{
    __shared__ int sb[64];
    int i0 = blockIdx.x * 64;
    int d = threadIdx.x;
    int iend = i0 + 64; if (iend > n) iend = n;
    int csize = iend - i0;
    if (d < csize) sb[d] = batch[i0 + d];
    __syncthreads();
    if (csize <= 0) return;
    float local = 0.f;
    int cur = sb[0];
    int runc = 0;
    for (int i = i0; i < iend; ++i) {
        int g = sb[i - i0];
        if (g != cur) {
            atomicAdd(&gsums[(size_t)cur * HD + d], local);
            if (d == 0) atomicAdd(&gcnt[cur], (float)runc);
            local = 0.f; runc = 0; cur = g;
        }
        local += h[(size_t)i * HD + d];
        runc++;
    }
    atomicAdd(&gsums[(size_t)cur * HD + d], local);
    if (d == 0) atomicAdd(&gcnt[cur], (float)runc);
}

// ---------------- classifier head: one block per graph ----------------
__global__ __launch_bounds__(128) void cls_kernel(
    const float* __restrict__ gsums, const float* __restrict__ gcnt,
    const float* __restrict__ cW1, const float* __restrict__ cb1,
    const float* __restrict__ cW2, const float* __restrict__ cb2,
    float* __restrict__ out)
{
    __shared__ float g[128];
    __shared__ float t[128];
    int gi = blockIdx.x, j = threadIdx.x;
    float c = fmaxf(gcnt[gi], 1.0f);
    g[j] = gsums[(size_t)gi * HD + j] / c;
    __syncthreads();
    float a = cb1[j];
    for (int k = 0; k < 128; ++k) a = fmaf(g[k], cW1[k * 128 + j], a);
    t[j] = fmaxf(a, 0.f);
    __syncthreads();
    if (j < 30) {
        float a2 = cb2[j];
        for (int k = 0; k < 128; ++k) a2 = fmaf(t[k], cW2[k * 30 + j], a2);
        out[gi * 30 + j] = a2;
    }
}

extern "C" void kernel_launch(void* const* d_in, const int* in_sizes, int n_in,
                              void* d_out, int out_size, void* d_ws, size_t ws_size,
                              hipStream_t stream)
{
    const float* x     = (const float*)d_in[0];
    const int*   ei    = (const int*)d_in[1];
    const float* eattr = (const float*)d_in[2];
    const int*   batch = (const int*)d_in[3];
    const float* l0_Wq = (const float*)d_in[4];
    const float* l0_bq = (const float*)d_in[5];
    const float* l0_Wk = (const float*)d_in[6];
    const float* l0_bk = (const float*)d_in[7];
    const float* l0_Wv = (const float*)d_in[8];
    const float* l0_bv = (const float*)d_in[9];
    const float* l0_We = (const float*)d_in[10];
    const float* l0_Ws = (const float*)d_in[11];
    const float* l0_bs = (const float*)d_in[12];
    const float* l1_Wq = (const float*)d_in[13];
    const float* l1_bq = (const float*)d_in[14];
    const float* l1_Wk = (const float*)d_in[15];
    const float* l1_bk = (const float*)d_in[16];
    const float* l1_Wv = (const float*)d_in[17];
    const float* l1_bv = (const float*)d_in[18];
    const float* l1_We = (const float*)d_in[19];
    const float* l1_Ws = (const float*)d_in[20];
    const float* l1_bs = (const float*)d_in[21];
    const float* cW1   = (const float*)d_in[22];
    const float* cb1   = (const float*)d_in[23];
    const float* cW2   = (const float*)d_in[24];
    const float* cb2   = (const float*)d_in[25];

    int n = in_sizes[0] / 2;     // 50000
    int E = in_sizes[2];         // 800000
    int G = out_size / 30;       // 64

    size_t nd = (size_t)n * HD;
    float* qbuf   = (float*)d_ws;                 // n*128
    float* kvbuf  = qbuf + nd;                    // n*256 (k/v interleaved per pair)
    float* sbuf   = kvbuf + 2 * nd;               // n*128
    float* h      = sbuf + nd;                    // n*128
    float* bias_cat = h + nd;                     // 512
    unsigned short* Wph = (unsigned short*)(bias_cat + 512);   // 65536
    unsigned short* Wpl = Wph + 65536;                         // 65536
    int2* epack   = (int2*)(Wpl + 65536);         // E
    int* cnt      = (int*)(epack + E);            // n
    int* row_ptr  = cnt + n;                      // n+1
    int* cursor   = row_ptr + n + 1;              // n
    float* gsums  = (float*)(cursor + n);         // G*128
    float* gcnt   = gsums + (size_t)G * HD;       // G

    const int* srcI = ei;
    const int* dstI = ei + E;

    hipMemsetAsync(cnt, 0, (size_t)n * sizeof(int), stream);
    hipMemsetAsync(gsums, 0, ((size_t)G * HD + G) * sizeof(float), stream);

    hist_kernel<<<(E + 255) / 256, 256, 0, stream>>>(dstI, cnt, E);
    scan_kernel<<<1, 1024, 0, stream>>>(cnt, row_ptr, cursor, n);
    scatter_kernel<<<(E + 255) / 256, 256, 0, stream>>>(dstI, srcI, eattr, cursor, epack, E);

    pack_kernel<<<256, 256, 0, stream>>>(l1_Wq, l1_Wk, l1_Wv, l1_Ws,
                                         l1_bq, l1_bk, l1_bv, l1_bs,
                                         Wph, Wpl, bias_cat);

    attn0_kernel<<<(n + 3) / 4, 256, 0, stream>>>(
        x, l0_Wq, l0_bq, l0_Wk, l0_bk, l0_Wv, l0_bv, l0_We, l0_Ws, l0_bs,
        epack, row_ptr, h, n);

    lin1_mfma<<<dim3((n + 63) / 64, 2), 256, 0, stream>>>(
        h, Wph, Wpl, bias_cat, qbuf, kvbuf, sbuf, n);
    attn_kernel<<<(n + 3) / 4, 256, 0, stream>>>(
        qbuf, kvbuf, sbuf, l1_We, epack, row_ptr, h, n);

    pool_kernel<<<(n + 63) / 64, 128, 0, stream>>>(h, batch, gsums, gcnt, n);
    cls_kernel<<<G, 128, 0, stream>>>(gsums, gcnt, cW1, cb1, cW2, cb2, (float*)d_out);
}

// Round 5
// 510.076 us; speedup vs baseline: 1.5759x; 1.1108x over previous
//
#include <hip/hip_runtime.h>
#include <hip/hip_fp16.h>
#include <cstdint>
#include <cstddef>

#define HD 128

typedef short bf16x8 __attribute__((ext_vector_type(8)));   // 8 bf16 in 4 VGPRs
typedef float f32x4 __attribute__((ext_vector_type(4)));

__device__ __forceinline__ unsigned short f2bf(float f) {
    unsigned int u = __float_as_uint(f);
    u += 0x7fff + ((u >> 16) & 1);          // round-to-nearest-even
    return (unsigned short)(u >> 16);
}
__device__ __forceinline__ float bf2f(unsigned short h) {
    return __uint_as_float(((unsigned int)h) << 16);
}

// DPP butterfly add (VALU pipe) — reduce within each 32-lane half (per head)
template<int CTRL>
__device__ __forceinline__ float dpp_add(float x) {
    int y = __builtin_amdgcn_update_dpp(0, __float_as_int(x), CTRL, 0xF, 0xF, true);
    return x + __int_as_float(y);
}
__device__ __forceinline__ float half_reduce(float x) {
    x = dpp_add<0xB1>(x);    // quad_perm xor1
    x = dpp_add<0x4E>(x);    // quad_perm xor2
    x = dpp_add<0x124>(x);   // row_ror:4
    x = dpp_add<0x128>(x);   // row_ror:8 -> row(16) sums
    x += __shfl_xor(x, 16, 64);  // combine two rows of the 32-half
    return x;
}

// fused dual online-softmax update, logits precomputed (no cross-lane in here)
__device__ __forceinline__ void pair_update_s(
    float& m, float& s, float2& acc,
    float lA, float lB,
    float vAx, float vAy, float vBx, float vBy)
{
    float nm = fmaxf(fmaxf(m, lA), lB);
    float sc = __expf(m - nm);
    float eA = __expf(lA - nm);
    float eB = __expf(lB - nm);
    s     = fmaf(s, sc, eA + eB);
    acc.x = fmaf(acc.x, sc, fmaf(eA, vAx, eB * vBx));
    acc.y = fmaf(acc.y, sc, fmaf(eA, vAy, eB * vBy));
    m = nm;
}
__device__ __forceinline__ void single_update_s(
    float& m, float& s, float2& acc,
    float lg, float vx, float vy)
{
    float nm = fmaxf(m, lg);
    float sc = __expf(m - nm);
    float ex = __expf(lg - nm);
    s     = fmaf(s, sc, ex);
    acc.x = fmaf(acc.x, sc, ex * vx);
    acc.y = fmaf(acc.y, sc, ex * vy);
    m = nm;
}

// ---------------- CSR-by-dst build ----------------
__global__ __launch_bounds__(256) void hist_kernel(
    const int* __restrict__ dst, int* __restrict__ cnt, int E)
{
    int e = blockIdx.x * 256 + threadIdx.x;
    if (e < E) atomicAdd(&cnt[dst[e]], 1);
}

__global__ __launch_bounds__(1024) void scan_kernel(
    const int* __restrict__ cnt, int* __restrict__ row_ptr,
    int* __restrict__ cursor, int n)
{
    __shared__ int sdata[1024];
    int t = threadIdx.x;
    int CH = (n + 1023) >> 10;
    int lo = t * CH;
    int hi = lo + CH; if (hi > n) hi = n;
    int local = 0;
    for (int i = lo; i < hi; ++i) local += cnt[i];
    sdata[t] = local;
    __syncthreads();
    for (int off = 1; off < 1024; off <<= 1) {
        int val = (t >= off) ? sdata[t - off] : 0;
        __syncthreads();
        sdata[t] += val;
        __syncthreads();
    }
    int run = sdata[t] - local;
    for (int i = lo; i < hi; ++i) {
        row_ptr[i] = run; cursor[i] = run;
        run += cnt[i];
    }
    if (t == 1023) row_ptr[n] = run;
}

__global__ __launch_bounds__(256) void scatter_kernel(
    const int* __restrict__ dst, const int* __restrict__ src,
    const float* __restrict__ eattr, int* __restrict__ cursor,
    int2* __restrict__ epack, int E)
{
    int e = blockIdx.x * 256 + threadIdx.x;
    if (e < E) {
        int pos = atomicAdd(&cursor[dst[e]], 1);
        epack[pos] = make_int2(src[e], __float_as_int(eattr[e]));
    }
}

// ---------------- layer-0 attention, fully fused; scalar-logit trick -----------
// logit = (x0*c0 + x1*c1 + cb + ea*cw)/8 with c0,c1,cb,cw per-node per-head
// precomputed by 4 reduces. Edge loop has ZERO cross-lane ops.
__global__ __launch_bounds__(256) void attn0_kernel(
    const float* __restrict__ x,
    const float* __restrict__ Wq, const float* __restrict__ bq,
    const float* __restrict__ Wk, const float* __restrict__ bk,
    const float* __restrict__ Wv, const float* __restrict__ bv,
    const float* __restrict__ We, const float* __restrict__ Ws,
    const float* __restrict__ bs,
    const int2* __restrict__ epack, const int* __restrict__ row_ptr,
    float* __restrict__ out, int n)
{
    int i = blockIdx.x * 4 + (threadIdx.x >> 6);
    if (i >= n) return;
    int l = threadIdx.x & 63;
    int j0 = 2 * l;

    float2 wk0 = *(const float2*)&Wk[j0];
    float2 wk1 = *(const float2*)&Wk[HD + j0];
    float2 wv0 = *(const float2*)&Wv[j0];
    float2 wv1 = *(const float2*)&Wv[HD + j0];
    float2 bk2 = *(const float2*)&bk[j0];
    float2 bv2 = *(const float2*)&bv[j0];
    float2 we  = *(const float2*)&We[j0];

    float x0 = x[2 * i], x1 = x[2 * i + 1];
    float2 wq0 = *(const float2*)&Wq[j0];
    float2 wq1 = *(const float2*)&Wq[HD + j0];
    float2 bq2 = *(const float2*)&bq[j0];
    float2 q;
    q.x = fmaf(x1, wq1.x, fmaf(x0, wq0.x, bq2.x));
    q.y = fmaf(x1, wq1.y, fmaf(x0, wq0.y, bq2.y));

    // per-head logit coefficients (head = 32-lane half), scaled by 1/8 up front
    float c0 = half_reduce(fmaf(q.x, wk0.x, q.y * wk0.y)) * 0.125f;
    float c1 = half_reduce(fmaf(q.x, wk1.x, q.y * wk1.y)) * 0.125f;
    float cb = half_reduce(fmaf(q.x, bk2.x, q.y * bk2.y)) * 0.125f;
    float cw = half_reduce(fmaf(q.x, we.x,  q.y * we.y))  * 0.125f;

    int p0 = __builtin_amdgcn_readfirstlane(row_ptr[i]);
    int p1 = __builtin_amdgcn_readfirstlane(row_ptr[i + 1]);

    float m = -INFINITY, s = 0.f;
    float2 acc = make_float2(0.f, 0.f);

    float2 xs0 = {}, xs1 = {}, xs2 = {}, xs3 = {};
    float ea0 = 0.f, ea1 = 0.f, ea2 = 0.f, ea3 = 0.f;

#define LD0(t, idx) do { if ((idx) < p1) { int2 ep_ = epack[idx]; \
    ea##t = __int_as_float(ep_.y); xs##t = *(const float2*)&x[2 * ep_.x]; } } while (0)

#define LOGIT0(xs, ea) fmaf(ea, cw, fmaf(xs.y, c1, fmaf(xs.x, c0, cb)))
#define VREC(xs, ea, vx, vy) \
    float vx = fmaf(ea, we.x, fmaf(xs.y, wv1.x, fmaf(xs.x, wv0.x, bv2.x))); \
    float vy = fmaf(ea, we.y, fmaf(xs.y, wv1.y, fmaf(xs.x, wv0.y, bv2.y)));

    LD0(0, p0); LD0(1, p0 + 1); LD0(2, p0 + 2); LD0(3, p0 + 3);

    int p = p0;
    for (; p + 3 < p1; p += 4) {
        float2 c0v = xs0, c1v = xs1, c2v = xs2, c3v = xs3;
        float a0 = ea0, a1 = ea1, a2 = ea2, a3 = ea3;
        LD0(0, p + 4); LD0(1, p + 5); LD0(2, p + 6); LD0(3, p + 7);
        { VREC(c0v, a0, vAx, vAy) VREC(c1v, a1, vBx, vBy)
          pair_update_s(m, s, acc, LOGIT0(c0v, a0), LOGIT0(c1v, a1), vAx, vAy, vBx, vBy); }
        { VREC(c2v, a2, vAx, vAy) VREC(c3v, a3, vBx, vBy)
          pair_update_s(m, s, acc, LOGIT0(c2v, a2), LOGIT0(c3v, a3), vAx, vAy, vBx, vBy); }
    }
    int rem = p1 - p;
    if (rem >= 2) {
        VREC(xs0, ea0, vAx, vAy) VREC(xs1, ea1, vBx, vBy)
        pair_update_s(m, s, acc, LOGIT0(xs0, ea0), LOGIT0(xs1, ea1), vAx, vAy, vBx, vBy);
    }
    if (rem == 1) {
        VREC(xs0, ea0, vx, vy)
        single_update_s(m, s, acc, LOGIT0(xs0, ea0), vx, vy);
    } else if (rem == 3) {
        VREC(xs2, ea2, vx, vy)
        single_update_s(m, s, acc, LOGIT0(xs2, ea2), vx, vy);
    }

    float inv = 1.f / (s + 1e-16f);
    float2 ws0 = *(const float2*)&Ws[j0];
    float2 ws1 = *(const float2*)&Ws[HD + j0];
    float2 bs2 = *(const float2*)&bs[j0];
    float sk_x = fmaf(x1, ws1.x, fmaf(x0, ws0.x, bs2.x));
    float sk_y = fmaf(x1, ws1.y, fmaf(x0, ws0.y, bs2.y));
    float2 res;
    res.x = fmaxf(fmaf(acc.x, inv, sk_x), 0.f);
    res.y = fmaxf(fmaf(acc.y, inv, sk_y), 0.f);
    *(float2*)&out[(size_t)i * HD + j0] = res;
}

// ---------------- layer-1 attention: fp16 kv gather (8B/lane), depth-4 pipeline ----
__global__ __launch_bounds__(256) void attn_kernel(
    const float* __restrict__ qbuf, const __half* __restrict__ kvh,
    const float* __restrict__ sbuf, const float* __restrict__ We,
    const int2* __restrict__ epack, const int* __restrict__ row_ptr,
    float* __restrict__ out, int n)
{
    int i = blockIdx.x * 4 + (threadIdx.x >> 6);
    if (i >= n) return;
    int l = threadIdx.x & 63;
    const int2* kv8 = (const int2*)kvh;   // 8B = (k2l,k2l+1,v2l,v2l+1) fp16
    float2 q  = *(const float2*)&qbuf[(size_t)i * HD + 2 * l];
    float2 we = *(const float2*)&We[2 * l];
    int p0 = __builtin_amdgcn_readfirstlane(row_ptr[i]);
    int p1 = __builtin_amdgcn_readfirstlane(row_ptr[i + 1]);

    float m = -INFINITY, s = 0.f;
    float2 acc = make_float2(0.f, 0.f);

    int2 kv0 = {}, kv1 = {}, kv2 = {}, kv3 = {};
    float ea0 = 0.f, ea1 = 0.f, ea2 = 0.f, ea3 = 0.f;

#define LD1(t, idx) do { if ((idx) < p1) { int2 ep_ = epack[idx]; \
    ea##t = __int_as_float(ep_.y); kv##t = kv8[(size_t)ep_.x * 64 + l]; } } while (0)

// expand fp16 kv + add ea*we; produce k and v floats
#define KVX(raw, ea, kx, ky, vx, vy) \
    float2 kf_##kx = __half22float2(*(const __half2*)&raw.x); \
    float2 vf_##kx = __half22float2(*(const __half2*)&raw.y); \
    float kx = fmaf(ea, we.x, kf_##kx.x), ky = fmaf(ea, we.y, kf_##kx.y); \
    float vx = fmaf(ea, we.x, vf_##kx.x), vy = fmaf(ea, we.y, vf_##kx.y);

    LD1(0, p0); LD1(1, p0 + 1); LD1(2, p0 + 2); LD1(3, p0 + 3);

    int p = p0;
    for (; p + 3 < p1; p += 4) {
        int2 c0 = kv0, c1 = kv1, c2 = kv2, c3 = kv3;
        float a0 = ea0, a1 = ea1, a2 = ea2, a3 = ea3;
        LD1(0, p + 4); LD1(1, p + 5); LD1(2, p + 6); LD1(3, p + 7);
        {
            KVX(c0, a0, kAx, kAy, vAx, vAy)
            KVX(c1, a1, kBx, kBy, vBx, vBy)
            float lA = half_reduce(fmaf(q.x, kAx, q.y * kAy)) * 0.125f;
            float lB = half_reduce(fmaf(q.x, kBx, q.y * kBy)) * 0.125f;
            pair_update_s(m, s, acc, lA, lB, vAx, vAy, vBx, vBy);
        }
        {
            KVX(c2, a2, kAx, kAy, vAx, vAy)
            KVX(c3, a3, kBx, kBy, vBx, vBy)
            float lA = half_reduce(fmaf(q.x, kAx, q.y * kAy)) * 0.125f;
            float lB = half_reduce(fmaf(q.x, kBx, q.y * kBy)) * 0.125f;
            pair_update_s(m, s, acc, lA, lB, vAx, vAy, vBx, vBy);
        }
    }
    int rem = p1 - p;
    if (rem >= 2) {
        KVX(kv0, ea0, kAx, kAy, vAx, vAy)
        KVX(kv1, ea1, kBx, kBy, vBx, vBy)
        float lA = half_reduce(fmaf(q.x, kAx, q.y * kAy)) * 0.125f;
        float lB = half_reduce(fmaf(q.x, kBx, q.y * kBy)) * 0.125f;
        pair_update_s(m, s, acc, lA, lB, vAx, vAy, vBx, vBy);
    }
    if (rem == 1) {
        KVX(kv0, ea0, kx, ky, vx, vy)
        single_update_s(m, s, acc, half_reduce(fmaf(q.x, kx, q.y * ky)) * 0.125f, vx, vy);
    } else if (rem == 3) {
        KVX(kv2, ea2, kx, ky, vx, vy)
        single_update_s(m, s, acc, half_reduce(fmaf(q.x, kx, q.y * ky)) * 0.125f, vx, vy);
    }

    float inv = 1.f / (s + 1e-16f);
    float2 skp = *(const float2*)&sbuf[(size_t)i * HD + 2 * l];
    float2 res;
    res.x = fmaxf(fmaf(acc.x, inv, skp.x), 0.f);
    res.y = fmaxf(fmaf(acc.y, inv, skp.y), 0.f);
    *(float2*)&out[(size_t)i * HD + 2 * l] = res;
}

// ---------------- W pre-pack: f32 [128,128]x4 -> mfma B-fragment order, bf16 hi/lo ----
__global__ __launch_bounds__(256) void pack_kernel(
    const float* __restrict__ Wq, const float* __restrict__ Wk,
    const float* __restrict__ Wv, const float* __restrict__ Ws,
    const float* __restrict__ bq, const float* __restrict__ bk,
    const float* __restrict__ bv, const float* __restrict__ bs,
    unsigned short* __restrict__ Wph, unsigned short* __restrict__ Wpl,
    float* __restrict__ bias_cat)
{
    int id = blockIdx.x * 256 + threadIdx.x;   // 65536 fragment entries
    if (id < 65536) {
        int j = id & 7, lane = (id >> 3) & 63, ks = (id >> 9) & 3, gnt = id >> 11;
        int k = ks * 32 + (lane >> 4) * 8 + j;
        int ncol = gnt * 16 + (lane & 15);
        int mat = ncol >> 7, d = ncol & 127;
        const float* W = (mat == 0) ? Wq : (mat == 1) ? Wk : (mat == 2) ? Wv : Ws;
        float w = W[k * HD + d];
        unsigned short hi = f2bf(w);
        Wph[id] = hi;
        Wpl[id] = f2bf(w - bf2f(hi));
    }
    if (id < 512) {
        int mat = id >> 7, d = id & 127;
        const float* b = (mat == 0) ? bq : (mat == 1) ? bk : (mat == 2) ? bv : bs;
        bias_cat[id] = b[d];
    }
}

// ---------------- layer-1 linears: [n,128] @ [128,512] via split-bf16 MFMA --------
__global__ __launch_bounds__(256) void lin1_mfma(
    const float* __restrict__ A,
    const unsigned short* __restrict__ Wph, const unsigned short* __restrict__ Wpl,
    const float* __restrict__ bias_cat,
    float* __restrict__ qbuf, __half* __restrict__ kvh, float* __restrict__ sbuf,
    int n)
{
    __shared__ float As[64 * 132];   // 33 KB, rows padded 128->132
    int tid = threadIdx.x;
    int row0 = blockIdx.x * 64;

    #pragma unroll
    for (int it = 0; it < 8; ++it) {
        int idx = it * 1024 + tid * 4;
        int r = idx >> 7, c = idx & 127;
        float4 av = make_float4(0.f, 0.f, 0.f, 0.f);
        if (row0 + r < n) av = *(const float4*)&A[(size_t)(row0 + r) * HD + c];
        *(float4*)&As[r * 132 + c] = av;
    }
    __syncthreads();

    int wave = tid >> 6, lane = tid & 63;
    int m = lane & 15, quad = lane >> 4;

    bf16x8 ah[4], al[4];
    const float* Arow = &As[(wave * 16 + m) * 132];
    #pragma unroll
    for (int ks = 0; ks < 4; ++ks) {
        float4 x0 = *(const float4*)&Arow[ks * 32 + quad * 8];
        float4 x1 = *(const float4*)&Arow[ks * 32 + quad * 8 + 4];
        float v[8] = {x0.x, x0.y, x0.z, x0.w, x1.x, x1.y, x1.z, x1.w};
        #pragma unroll
        for (int j = 0; j < 8; ++j) {
            unsigned short hi = f2bf(v[j]);
            ah[ks][j] = (short)hi;
            al[ks][j] = (short)f2bf(v[j] - bf2f(hi));
        }
    }

    const bf16x8* PH = (const bf16x8*)Wph;
    const bf16x8* PL = (const bf16x8*)Wpl;

    for (int nt = 0; nt < 16; ++nt) {
        int gnt = blockIdx.y * 16 + nt;
        f32x4 acc = {0.f, 0.f, 0.f, 0.f};
        #pragma unroll
        for (int ks = 0; ks < 4; ++ks) {
            bf16x8 bh = PH[(gnt * 4 + ks) * 64 + lane];
            bf16x8 bl = PL[(gnt * 4 + ks) * 64 + lane];
            acc = __builtin_amdgcn_mfma_f32_16x16x32_bf16(ah[ks], bh, acc, 0, 0, 0);
            acc = __builtin_amdgcn_mfma_f32_16x16x32_bf16(ah[ks], bl, acc, 0, 0, 0);
            acc = __builtin_amdgcn_mfma_f32_16x16x32_bf16(al[ks], bh, acc, 0, 0, 0);
        }
        int ocol = gnt * 16 + m;
        int mat = ocol >> 7, d = ocol & 127;
        float bias = bias_cat[ocol];
        #pragma unroll
        for (int reg = 0; reg < 4; ++reg) {
            int orow = row0 + wave * 16 + quad * 4 + reg;
            if (orow < n) {
                float val = acc[reg] + bias;
                if (mat == 0)      qbuf[(size_t)orow * HD + d] = val;
                else if (mat == 1) kvh[(size_t)orow * 256 + (d >> 1) * 4 + (d & 1)] = __float2half(val);
                else if (mat == 2) kvh[(size_t)orow * 256 + (d >> 1) * 4 + 2 + (d & 1)] = __float2half(val);
                else               sbuf[(size_t)orow * HD + d] = val;
            }
        }
    }
}

// ---------------- mean-pool (batch sorted -> run-length partials) ----------------
__global__ __launch_bounds__(128) void pool_kernel(
    const float* __restrict__ h, const int* __restrict__ batch,
    float* __restrict__ gsums, float* __restrict__ gcnt, int n)
{
    __shared__ int sb[64];
    int i0 = blockIdx.x * 64;
    int d = threadIdx.x;
    int iend = i0 + 64; if (iend > n) iend = n;
    int csize = iend - i0;
    if (d < csize) sb[d] = batch[i0 + d];
    __syncthreads();
    if (csize <= 0) return;
    float local = 0.f;
    int cur = sb[0];
    int runc = 0;
    for (int i = i0; i < iend; ++i) {
        int g = sb[i - i0];
        if (g != cur) {
            atomicAdd(&gsums[(size_t)cur * HD + d], local);
            if (d == 0) atomicAdd(&gcnt[cur], (float)runc);
            local = 0.f; runc = 0; cur = g;
        }
        local += h[(size_t)i * HD + d];
        runc++;
    }
    atomicAdd(&gsums[(size_t)cur * HD + d], local);
    if (d == 0) atomicAdd(&gcnt[cur], (float)runc);
}

// ---------------- classifier head: one block per graph ----------------
__global__ __launch_bounds__(128) void cls_kernel(
    const float* __restrict__ gsums, const float* __restrict__ gcnt,
    const float* __restrict__ cW1, const float* __restrict__ cb1,
    const float* __restrict__ cW2, const float* __restrict__ cb2,
    float* __restrict__ out)
{
    __shared__ float g[128];
    __shared__ float t[128];
    int gi = blockIdx.x, j = threadIdx.x;
    float c = fmaxf(gcnt[gi], 1.0f);
    g[j] = gsums[(size_t)gi * HD + j] / c;
    __syncthreads();
    float a = cb1[j];
    for (int k = 0; k < 128; ++k) a = fmaf(g[k], cW1[k * 128 + j], a);
    t[j] = fmaxf(a, 0.f);
    __syncthreads();
    if (j < 30) {
        float a2 = cb2[j];
        for (int k = 0; k < 128; ++k) a2 = fmaf(t[k], cW2[k * 30 + j], a2);
        out[gi * 30 + j] = a2;
    }
}

extern "C" void kernel_launch(void* const* d_in, const int* in_sizes, int n_in,
                              void* d_out, int out_size, void* d_ws, size_t ws_size,
                              hipStream_t stream)
{
    const float* x     = (const float*)d_in[0];
    const int*   ei    = (const int*)d_in[1];
    const float* eattr = (const float*)d_in[2];
    const int*   batch = (const int*)d_in[3];
    const float* l0_Wq = (const float*)d_in[4];
    const float* l0_bq = (const float*)d_in[5];
    const float* l0_Wk = (const float*)d_in[6];
    const float* l0_bk = (const float*)d_in[7];
    const float* l0_Wv = (const float*)d_in[8];
    const float* l0_bv = (const float*)d_in[9];
    const float* l0_We = (const float*)d_in[10];
    const float* l0_Ws = (const float*)d_in[11];
    const float* l0_bs = (const float*)d_in[12];
    const float* l1_Wq = (const float*)d_in[13];
    const float* l1_bq = (const float*)d_in[14];
    const float* l1_Wk = (const float*)d_in[15];
    const float* l1_bk = (const float*)d_in[16];
    const float* l1_Wv = (const float*)d_in[17];
    const float* l1_bv = (const float*)d_in[18];
    const float* l1_We = (const float*)d_in[19];
    const float* l1_Ws = (const float*)d_in[20];
    const float* l1_bs = (const float*)d_in[21];
    const float* cW1   = (const float*)d_in[22];
    const float* cb1   = (const float*)d_in[23];
    const float* cW2   = (const float*)d_in[24];
    const float* cb2   = (const float*)d_in[25];

    int n = in_sizes[0] / 2;     // 50000
    int E = in_sizes[2];         // 800000
    int G = out_size / 30;       // 64

    size_t nd = (size_t)n * HD;
    float* qbuf   = (float*)d_ws;                 // n*128 f32
    float* sbuf   = qbuf + nd;                    // n*128 f32
    float* h      = sbuf + nd;                    // n*128 f32
    __half* kvh   = (__half*)(h + nd);            // n*256 fp16 (interleaved kv pairs)
    float* bias_cat = (float*)(kvh + (size_t)n * 256);         // 512
    unsigned short* Wph = (unsigned short*)(bias_cat + 512);   // 65536
    unsigned short* Wpl = Wph + 65536;                         // 65536
    int2* epack   = (int2*)(Wpl + 65536);         // E
    int* cnt      = (int*)(epack + E);            // n
    int* row_ptr  = cnt + n;                      // n+1
    int* cursor   = row_ptr + n + 1;              // n
    float* gsums  = (float*)(cursor + n);         // G*128
    float* gcnt   = gsums + (size_t)G * HD;       // G

    const int* srcI = ei;
    const int* dstI = ei + E;

    hipMemsetAsync(cnt, 0, (size_t)n * sizeof(int), stream);
    hipMemsetAsync(gsums, 0, ((size_t)G * HD + G) * sizeof(float), stream);

    hist_kernel<<<(E + 255) / 256, 256, 0, stream>>>(dstI, cnt, E);
    scan_kernel<<<1, 1024, 0, stream>>>(cnt, row_ptr, cursor, n);
    scatter_kernel<<<(E + 255) / 256, 256, 0, stream>>>(dstI, srcI, eattr, cursor, epack, E);

    pack_kernel<<<256, 256, 0, stream>>>(l1_Wq, l1_Wk, l1_Wv, l1_Ws,
                                         l1_bq, l1_bk, l1_bv, l1_bs,
                                         Wph, Wpl, bias_cat);

    attn0_kernel<<<(n + 3) / 4, 256, 0, stream>>>(
        x, l0_Wq, l0_bq, l0_Wk, l0_bk, l0_Wv, l0_bv, l0_We, l0_Ws, l0_bs,
        epack, row_ptr, h, n);

    lin1_mfma<<<dim3((n + 63) / 64, 2), 256, 0, stream>>>(
        h, Wph, Wpl, bias_cat, qbuf, kvh, sbuf, n);
    attn_kernel<<<(n + 3) / 4, 256, 0, stream>>>(
        qbuf, kvh, sbuf, l1_We, epack, row_ptr, h, n);

    pool_kernel<<<(n + 63) / 64, 128, 0, stream>>>(h, batch, gsums, gcnt, n);
    cls_kernel<<<G, 128, 0, stream>>>(gsums, gcnt, cW1, cb1, cW2, cb2, (float*)d_out);
}

// Round 6
// 404.924 us; speedup vs baseline: 1.9852x; 1.2597x over previous
//
#include <hip/hip_runtime.h>
#include <hip/hip_fp16.h>
#include <cstdint>
#include <cstddef>

#define HD 128

typedef short bf16x8 __attribute__((ext_vector_type(8)));   // 8 bf16 in 4 VGPRs
typedef float f32x4 __attribute__((ext_vector_type(4)));

__device__ __forceinline__ unsigned short f2bf(float f) {
    unsigned int u = __float_as_uint(f);
    u += 0x7fff + ((u >> 16) & 1);          // round-to-nearest-even
    return (unsigned short)(u >> 16);
}
__device__ __forceinline__ float bf2f(unsigned short h) {
    return __uint_as_float(((unsigned int)h) << 16);
}

// DPP butterfly add (VALU pipe) — reduce within each 32-lane half (per head)
template<int CTRL>
__device__ __forceinline__ float dpp_add(float x) {
    int y = __builtin_amdgcn_update_dpp(0, __float_as_int(x), CTRL, 0xF, 0xF, true);
    return x + __int_as_float(y);
}
__device__ __forceinline__ float half_reduce(float x) {
    x = dpp_add<0xB1>(x);    // quad_perm xor1
    x = dpp_add<0x4E>(x);    // quad_perm xor2
    x = dpp_add<0x124>(x);   // row_ror:4
    x = dpp_add<0x128>(x);   // row_ror:8 -> row(16) sums
    x += __shfl_xor(x, 16, 64);  // combine two rows of the 32-half
    return x;
}

// fused dual online-softmax update, logits precomputed
__device__ __forceinline__ void pair_update_s(
    float& m, float& s, float2& acc,
    float lA, float lB,
    float vAx, float vAy, float vBx, float vBy)
{
    float nm = fmaxf(fmaxf(m, lA), lB);
    float sc = __expf(m - nm);
    float eA = __expf(lA - nm);
    float eB = __expf(lB - nm);
    s     = fmaf(s, sc, eA + eB);
    acc.x = fmaf(acc.x, sc, fmaf(eA, vAx, eB * vBx));
    acc.y = fmaf(acc.y, sc, fmaf(eA, vAy, eB * vBy));
    m = nm;
}
__device__ __forceinline__ void single_update_s(
    float& m, float& s, float2& acc,
    float lg, float vx, float vy)
{
    float nm = fmaxf(m, lg);
    float sc = __expf(m - nm);
    float ex = __expf(lg - nm);
    s     = fmaf(s, sc, ex);
    acc.x = fmaf(acc.x, sc, ex * vx);
    acc.y = fmaf(acc.y, sc, ex * vy);
    m = nm;
}

// ---------------- CSR-by-dst build ----------------
__global__ __launch_bounds__(256) void hist_kernel(
    const int* __restrict__ dst, int* __restrict__ cnt, int E)
{
    int e = blockIdx.x * 256 + threadIdx.x;
    if (e < E) atomicAdd(&cnt[dst[e]], 1);
}

// 3-phase hierarchical exclusive scan (512 elems/block in LDS)
__global__ __launch_bounds__(256) void scanA_kernel(
    const int* __restrict__ cnt, int* __restrict__ row_ptr,
    int* __restrict__ bsum, int n)
{
    __shared__ int sdata[256];
    int t = threadIdx.x;
    int base = blockIdx.x * 512 + 2 * t;
    int a = (base < n) ? cnt[base] : 0;
    int b = (base + 1 < n) ? cnt[base + 1] : 0;
    int local = a + b;
    sdata[t] = local;
    __syncthreads();
    #pragma unroll
    for (int off = 1; off < 256; off <<= 1) {
        int val = (t >= off) ? sdata[t - off] : 0;
        __syncthreads();
        sdata[t] += val;
        __syncthreads();
    }
    int excl = sdata[t] - local;
    if (base < n)     row_ptr[base] = excl;
    if (base + 1 < n) row_ptr[base + 1] = excl + a;
    if (t == 255) bsum[blockIdx.x] = sdata[255];
}

__global__ __launch_bounds__(256) void scanB_kernel(
    const int* __restrict__ bsum, int* __restrict__ boff, int B)
{
    __shared__ int sdata[256];
    int t = threadIdx.x;
    int local = (t < B) ? bsum[t] : 0;
    sdata[t] = local;
    __syncthreads();
    #pragma unroll
    for (int off = 1; off < 256; off <<= 1) {
        int val = (t >= off) ? sdata[t - off] : 0;
        __syncthreads();
        sdata[t] += val;
        __syncthreads();
    }
    if (t < B) boff[t] = sdata[t] - local;
}

__global__ __launch_bounds__(256) void scanC_kernel(
    int* __restrict__ row_ptr, int* __restrict__ cursor,
    const int* __restrict__ boff, int n, int E)
{
    int t = threadIdx.x;
    int base = blockIdx.x * 512 + 2 * t;
    int off = boff[blockIdx.x];
    if (base + 1 < n) {
        int2 v = *(int2*)&row_ptr[base];
        v.x += off; v.y += off;
        *(int2*)&row_ptr[base] = v;
        *(int2*)&cursor[base]  = v;
    } else if (base < n) {
        int v = row_ptr[base] + off;
        row_ptr[base] = v; cursor[base] = v;
    }
    if (blockIdx.x == 0 && t == 0) row_ptr[n] = E;
}

__global__ __launch_bounds__(256) void scatter_kernel(
    const int* __restrict__ dst, const int* __restrict__ src,
    const float* __restrict__ eattr, int* __restrict__ cursor,
    int2* __restrict__ epack, int E)
{
    int e = blockIdx.x * 256 + threadIdx.x;
    if (e < E) {
        int pos = atomicAdd(&cursor[dst[e]], 1);
        epack[pos] = make_int2(src[e], __float_as_int(eattr[e]));
    }
}

// ---------------- layer-0 attention, fully fused; scalar-logit trick -----------
__global__ __launch_bounds__(256) void attn0_kernel(
    const float* __restrict__ x,
    const float* __restrict__ Wq, const float* __restrict__ bq,
    const float* __restrict__ Wk, const float* __restrict__ bk,
    const float* __restrict__ Wv, const float* __restrict__ bv,
    const float* __restrict__ We, const float* __restrict__ Ws,
    const float* __restrict__ bs,
    const int2* __restrict__ epack, const int* __restrict__ row_ptr,
    float* __restrict__ out, int n)
{
    int i = blockIdx.x * 4 + (threadIdx.x >> 6);
    if (i >= n) return;
    int l = threadIdx.x & 63;
    int j0 = 2 * l;

    float2 wk0 = *(const float2*)&Wk[j0];
    float2 wk1 = *(const float2*)&Wk[HD + j0];
    float2 wv0 = *(const float2*)&Wv[j0];
    float2 wv1 = *(const float2*)&Wv[HD + j0];
    float2 bk2 = *(const float2*)&bk[j0];
    float2 bv2 = *(const float2*)&bv[j0];
    float2 we  = *(const float2*)&We[j0];

    float x0 = x[2 * i], x1 = x[2 * i + 1];
    float2 wq0 = *(const float2*)&Wq[j0];
    float2 wq1 = *(const float2*)&Wq[HD + j0];
    float2 bq2 = *(const float2*)&bq[j0];
    float2 q;
    q.x = fmaf(x1, wq1.x, fmaf(x0, wq0.x, bq2.x));
    q.y = fmaf(x1, wq1.y, fmaf(x0, wq0.y, bq2.y));

    float c0 = half_reduce(fmaf(q.x, wk0.x, q.y * wk0.y)) * 0.125f;
    float c1 = half_reduce(fmaf(q.x, wk1.x, q.y * wk1.y)) * 0.125f;
    float cb = half_reduce(fmaf(q.x, bk2.x, q.y * bk2.y)) * 0.125f;
    float cw = half_reduce(fmaf(q.x, we.x,  q.y * we.y))  * 0.125f;

    int p0 = __builtin_amdgcn_readfirstlane(row_ptr[i]);
    int p1 = __builtin_amdgcn_readfirstlane(row_ptr[i + 1]);

    float m = -INFINITY, s = 0.f;
    float2 acc = make_float2(0.f, 0.f);

    float2 xs0 = {}, xs1 = {}, xs2 = {}, xs3 = {};
    float ea0 = 0.f, ea1 = 0.f, ea2 = 0.f, ea3 = 0.f;

#define LD0(t, idx) do { if ((idx) < p1) { int2 ep_ = epack[idx]; \
    ea##t = __int_as_float(ep_.y); xs##t = *(const float2*)&x[2 * ep_.x]; } } while (0)

#define LOGIT0(xs, ea) fmaf(ea, cw, fmaf(xs.y, c1, fmaf(xs.x, c0, cb)))
#define VREC(xs, ea, vx, vy) \
    float vx = fmaf(ea, we.x, fmaf(xs.y, wv1.x, fmaf(xs.x, wv0.x, bv2.x))); \
    float vy = fmaf(ea, we.y, fmaf(xs.y, wv1.y, fmaf(xs.x, wv0.y, bv2.y)));

    LD0(0, p0); LD0(1, p0 + 1); LD0(2, p0 + 2); LD0(3, p0 + 3);

    int p = p0;
    for (; p + 3 < p1; p += 4) {
        float2 c0v = xs0, c1v = xs1, c2v = xs2, c3v = xs3;
        float a0 = ea0, a1 = ea1, a2 = ea2, a3 = ea3;
        LD0(0, p + 4); LD0(1, p + 5); LD0(2, p + 6); LD0(3, p + 7);
        { VREC(c0v, a0, vAx, vAy) VREC(c1v, a1, vBx, vBy)
          pair_update_s(m, s, acc, LOGIT0(c0v, a0), LOGIT0(c1v, a1), vAx, vAy, vBx, vBy); }
        { VREC(c2v, a2, vAx, vAy) VREC(c3v, a3, vBx, vBy)
          pair_update_s(m, s, acc, LOGIT0(c2v, a2), LOGIT0(c3v, a3), vAx, vAy, vBx, vBy); }
    }
    int rem = p1 - p;
    if (rem >= 2) {
        VREC(xs0, ea0, vAx, vAy) VREC(xs1, ea1, vBx, vBy)
        pair_update_s(m, s, acc, LOGIT0(xs0, ea0), LOGIT0(xs1, ea1), vAx, vAy, vBx, vBy);
    }
    if (rem == 1) {
        VREC(xs0, ea0, vx, vy)
        single_update_s(m, s, acc, LOGIT0(xs0, ea0), vx, vy);
    } else if (rem == 3) {
        VREC(xs2, ea2, vx, vy)
        single_update_s(m, s, acc, LOGIT0(xs2, ea2), vx, vy);
    }

    float inv = 1.f / (s + 1e-16f);
    float2 ws0 = *(const float2*)&Ws[j0];
    float2 ws1 = *(const float2*)&Ws[HD + j0];
    float2 bs2 = *(const float2*)&bs[j0];
    float sk_x = fmaf(x1, ws1.x, fmaf(x0, ws0.x, bs2.x));
    float sk_y = fmaf(x1, ws1.y, fmaf(x0, ws0.y, bs2.y));
    float2 res;
    res.x = fmaxf(fmaf(acc.x, inv, sk_x), 0.f);
    res.y = fmaxf(fmaf(acc.y, inv, sk_y), 0.f);
    *(float2*)&out[(size_t)i * HD + j0] = res;
}

// ---------------- layer-1 attention: fp16 kv gather (8B/lane), depth-4 pipeline ----
__global__ __launch_bounds__(256) void attn_kernel(
    const float* __restrict__ qbuf, const __half* __restrict__ kvh,
    const float* __restrict__ sbuf, const float* __restrict__ We,
    const int2* __restrict__ epack, const int* __restrict__ row_ptr,
    float* __restrict__ out, int n)
{
    int i = blockIdx.x * 4 + (threadIdx.x >> 6);
    if (i >= n) return;
    int l = threadIdx.x & 63;
    const int2* kv8 = (const int2*)kvh;   // 8B = (k2l,k2l+1,v2l,v2l+1) fp16
    float2 q  = *(const float2*)&qbuf[(size_t)i * HD + 2 * l];
    float2 we = *(const float2*)&We[2 * l];
    int p0 = __builtin_amdgcn_readfirstlane(row_ptr[i]);
    int p1 = __builtin_amdgcn_readfirstlane(row_ptr[i + 1]);

    float m = -INFINITY, s = 0.f;
    float2 acc = make_float2(0.f, 0.f);

    int2 kv0 = {}, kv1 = {}, kv2 = {}, kv3 = {};
    float ea0 = 0.f, ea1 = 0.f, ea2 = 0.f, ea3 = 0.f;

#define LD1(t, idx) do { if ((idx) < p1) { int2 ep_ = epack[idx]; \
    ea##t = __int_as_float(ep_.y); kv##t = kv8[(size_t)ep_.x * 64 + l]; } } while (0)

#define KVX(raw, ea, kx, ky, vx, vy) \
    float2 kf_##kx = __half22float2(*(const __half2*)&raw.x); \
    float2 vf_##kx = __half22float2(*(const __half2*)&raw.y); \
    float kx = fmaf(ea, we.x, kf_##kx.x), ky = fmaf(ea, we.y, kf_##kx.y); \
    float vx = fmaf(ea, we.x, vf_##kx.x), vy = fmaf(ea, we.y, vf_##kx.y);

    LD1(0, p0); LD1(1, p0 + 1); LD1(2, p0 + 2); LD1(3, p0 + 3);

    int p = p0;
    for (; p + 3 < p1; p += 4) {
        int2 c0 = kv0, c1 = kv1, c2 = kv2, c3 = kv3;
        float a0 = ea0, a1 = ea1, a2 = ea2, a3 = ea3;
        LD1(0, p + 4); LD1(1, p + 5); LD1(2, p + 6); LD1(3, p + 7);
        {
            KVX(c0, a0, kAx, kAy, vAx, vAy)
            KVX(c1, a1, kBx, kBy, vBx, vBy)
            float lA = half_reduce(fmaf(q.x, kAx, q.y * kAy)) * 0.125f;
            float lB = half_reduce(fmaf(q.x, kBx, q.y * kBy)) * 0.125f;
            pair_update_s(m, s, acc, lA, lB, vAx, vAy, vBx, vBy);
        }
        {
            KVX(c2, a2, kAx, kAy, vAx, vAy)
            KVX(c3, a3, kBx, kBy, vBx, vBy)
            float lA = half_reduce(fmaf(q.x, kAx, q.y * kAy)) * 0.125f;
            float lB = half_reduce(fmaf(q.x, kBx, q.y * kBy)) * 0.125f;
            pair_update_s(m, s, acc, lA, lB, vAx, vAy, vBx, vBy);
        }
    }
    int rem = p1 - p;
    if (rem >= 2) {
        KVX(kv0, ea0, kAx, kAy, vAx, vAy)
        KVX(kv1, ea1, kBx, kBy, vBx, vBy)
        float lA = half_reduce(fmaf(q.x, kAx, q.y * kAy)) * 0.125f;
        float lB = half_reduce(fmaf(q.x, kBx, q.y * kBy)) * 0.125f;
        pair_update_s(m, s, acc, lA, lB, vAx, vAy, vBx, vBy);
    }
    if (rem == 1) {
        KVX(kv0, ea0, kx, ky, vx, vy)
        single_update_s(m, s, acc, half_reduce(fmaf(q.x, kx, q.y * ky)) * 0.125f, vx, vy);
    } else if (rem == 3) {
        KVX(kv2, ea2, kx, ky, vx, vy)
        single_update_s(m, s, acc, half_reduce(fmaf(q.x, kx, q.y * ky)) * 0.125f, vx, vy);
    }

    float inv = 1.f / (s + 1e-16f);
    float2 skp = *(const float2*)&sbuf[(size_t)i * HD + 2 * l];
    float2 res;
    res.x = fmaxf(fmaf(acc.x, inv, skp.x), 0.f);
    res.y = fmaxf(fmaf(acc.y, inv, skp.y), 0.f);
    *(float2*)&out[(size_t)i * HD + 2 * l] = res;
}

// ---------------- W pre-pack: f32 [128,128]x4 -> mfma B-fragment order, bf16 hi/lo ----
__global__ __launch_bounds__(256) void pack_kernel(
    const float* __restrict__ Wq, const float* __restrict__ Wk,
    const float* __restrict__ Wv, const float* __restrict__ Ws,
    const float* __restrict__ bq, const float* __restrict__ bk,
    const float* __restrict__ bv, const float* __restrict__ bs,
    unsigned short* __restrict__ Wph, unsigned short* __restrict__ Wpl,
    float* __restrict__ bias_cat)
{
    int id = blockIdx.x * 256 + threadIdx.x;   // 65536 fragment entries
    if (id < 65536) {
        int j = id & 7, lane = (id >> 3) & 63, ks = (id >> 9) & 3, gnt = id >> 11;
        int k = ks * 32 + (lane >> 4) * 8 + j;
        int ncol = gnt * 16 + (lane & 15);
        int mat = ncol >> 7, d = ncol & 127;
        const float* W = (mat == 0) ? Wq : (mat == 1) ? Wk : (mat == 2) ? Wv : Ws;
        float w = W[k * HD + d];
        unsigned short hi = f2bf(w);
        Wph[id] = hi;
        Wpl[id] = f2bf(w - bf2f(hi));
    }
    if (id < 512) {
        int mat = id >> 7, d = id & 127;
        const float* b = (mat == 0) ? bq : (mat == 1) ? bk : (mat == 2) ? bv : bs;
        bias_cat[id] = b[d];
    }
}

// ---------------- layer-1 linears: [n,128] @ [128,512] via split-bf16 MFMA --------
__global__ __launch_bounds__(256) void lin1_mfma(
    const float* __restrict__ A,
    const unsigned short* __restrict__ Wph, const unsigned short* __restrict__ Wpl,
    const float* __restrict__ bias_cat,
    float* __restrict__ qbuf, __half* __restrict__ kvh, float* __restrict__ sbuf,
    int n)
{
    __shared__ float As[64 * 132];   // 33 KB, rows padded 128->132
    int tid = threadIdx.x;
    int row0 = blockIdx.x * 64;

    #pragma unroll
    for (int it = 0; it < 8; ++it) {
        int idx = it * 1024 + tid * 4;
        int r = idx >> 7, c = idx & 127;
        float4 av = make_float4(0.f, 0.f, 0.f, 0.f);
        if (row0 + r < n) av = *(const float4*)&A[(size_t)(row0 + r) * HD + c];
        *(float4*)&As[r * 132 + c] = av;
    }
    __syncthreads();

    int wave = tid >> 6, lane = tid & 63;
    int m = lane & 15, quad = lane >> 4;

    bf16x8 ah[4], al[4];
    const float* Arow = &As[(wave * 16 + m) * 132];
    #pragma unroll
    for (int ks = 0; ks < 4; ++ks) {
        float4 x0 = *(const float4*)&Arow[ks * 32 + quad * 8];
        float4 x1 = *(const float4*)&Arow[ks * 32 + quad * 8 + 4];
        float v[8] = {x0.x, x0.y, x0.z, x0.w, x1.x, x1.y, x1.z, x1.w};
        #pragma unroll
        for (int j = 0; j < 8; ++j) {
            unsigned short hi = f2bf(v[j]);
            ah[ks][j] = (short)hi;
            al[ks][j] = (short)f2bf(v[j] - bf2f(hi));
        }
    }

    const bf16x8* PH = (const bf16x8*)Wph;
    const bf16x8* PL = (const bf16x8*)Wpl;

    for (int nt = 0; nt < 16; ++nt) {
        int gnt = blockIdx.y * 16 + nt;
        f32x4 acc = {0.f, 0.f, 0.f, 0.f};
        #pragma unroll
        for (int ks = 0; ks < 4; ++ks) {
            bf16x8 bh = PH[(gnt * 4 + ks) * 64 + lane];
            bf16x8 bl = PL[(gnt * 4 + ks) * 64 + lane];
            acc = __builtin_amdgcn_mfma_f32_16x16x32_bf16(ah[ks], bh, acc, 0, 0, 0);
            acc = __builtin_amdgcn_mfma_f32_16x16x32_bf16(ah[ks], bl, acc, 0, 0, 0);
            acc = __builtin_amdgcn_mfma_f32_16x16x32_bf16(al[ks], bh, acc, 0, 0, 0);
        }
        int ocol = gnt * 16 + m;
        int mat = ocol >> 7, d = ocol & 127;
        float bias = bias_cat[ocol];
        #pragma unroll
        for (int reg = 0; reg < 4; ++reg) {
            int orow = row0 + wave * 16 + quad * 4 + reg;
            if (orow < n) {
                float val = acc[reg] + bias;
                if (mat == 0)      qbuf[(size_t)orow * HD + d] = val;
                else if (mat == 1) kvh[(size_t)orow * 256 + (d >> 1) * 4 + (d & 1)] = __float2half(val);
                else if (mat == 2) kvh[(size_t)orow * 256 + (d >> 1) * 4 + 2 + (d & 1)] = __float2half(val);
                else               sbuf[(size_t)orow * HD + d] = val;
            }
        }
    }
}

// ---------------- mean-pool (batch sorted -> run-length partials) ----------------
__global__ __launch_bounds__(128) void pool_kernel(
    const float* __restrict__ h, const int* __restrict__ batch,
    float* __restrict__ gsums, float* __restrict__ gcnt, int n)
{
    __shared__ int sb[64];
    int i0 = blockIdx.x * 64;
    int d = threadIdx.x;
    int iend = i0 + 64; if (iend > n) iend = n;
    int csize = iend - i0;
    if (d < csize) sb[d] = batch[i0 + d];
    __syncthreads();
    if (csize <= 0) return;
    float local = 0.f;
    int cur = sb[0];
    int runc = 0;
    for (int i = i0; i < iend; ++i) {
        int g = sb[i - i0];
        if (g != cur) {
            atomicAdd(&gsums[(size_t)cur * HD + d], local);
            if (d == 0) atomicAdd(&gcnt[cur], (float)runc);
            local = 0.f; runc = 0; cur = g;
        }
        local += h[(size_t)i * HD + d];
        runc++;
    }
    atomicAdd(&gsums[(size_t)cur * HD + d], local);
    if (d == 0) atomicAdd(&gcnt[cur], (float)runc);
}

// ---------------- classifier head: one block per graph ----------------
__global__ __launch_bounds__(128) void cls_kernel(
    const float* __restrict__ gsums, const float* __restrict__ gcnt,
    const float* __restrict__ cW1, const float* __restrict__ cb1,
    const float* __restrict__ cW2, const float* __restrict__ cb2,
    float* __restrict__ out)
{
    __shared__ float g[128];
    __shared__ float t[128];
    int gi = blockIdx.x, j = threadIdx.x;
    float c = fmaxf(gcnt[gi], 1.0f);
    g[j] = gsums[(size_t)gi * HD + j] / c;
    __syncthreads();
    float a = cb1[j];
    for (int k = 0; k < 128; ++k) a = fmaf(g[k], cW1[k * 128 + j], a);
    t[j] = fmaxf(a, 0.f);
    __syncthreads();
    if (j < 30) {
        float a2 = cb2[j];
        for (int k = 0; k < 128; ++k) a2 = fmaf(t[k], cW2[k * 30 + j], a2);
        out[gi * 30 + j] = a2;
    }
}

extern "C" void kernel_launch(void* const* d_in, const int* in_sizes, int n_in,
                              void* d_out, int out_size, void* d_ws, size_t ws_size,
                              hipStream_t stream)
{
    const float* x     = (const float*)d_in[0];
    const int*   ei    = (const int*)d_in[1];
    const float* eattr = (const float*)d_in[2];
    const int*   batch = (const int*)d_in[3];
    const float* l0_Wq = (const float*)d_in[4];
    const float* l0_bq = (const float*)d_in[5];
    const float* l0_Wk = (const float*)d_in[6];
    const float* l0_bk = (const float*)d_in[7];
    const float* l0_Wv = (const float*)d_in[8];
    const float* l0_bv = (const float*)d_in[9];
    const float* l0_We = (const float*)d_in[10];
    const float* l0_Ws = (const float*)d_in[11];
    const float* l0_bs = (const float*)d_in[12];
    const float* l1_Wq = (const float*)d_in[13];
    const float* l1_bq = (const float*)d_in[14];
    const float* l1_Wk = (const float*)d_in[15];
    const float* l1_bk = (const float*)d_in[16];
    const float* l1_Wv = (const float*)d_in[17];
    const float* l1_bv = (const float*)d_in[18];
    const float* l1_We = (const float*)d_in[19];
    const float* l1_Ws = (const float*)d_in[20];
    const float* l1_bs = (const float*)d_in[21];
    const float* cW1   = (const float*)d_in[22];
    const float* cb1   = (const float*)d_in[23];
    const float* cW2   = (const float*)d_in[24];
    const float* cb2   = (const float*)d_in[25];

    int n = in_sizes[0] / 2;     // 50000
    int E = in_sizes[2];         // 800000
    int G = out_size / 30;       // 64
    int B = (n + 511) / 512;     // scan blocks (98)

    size_t nd = (size_t)n * HD;
    float* qbuf   = (float*)d_ws;                 // n*128 f32
    float* sbuf   = qbuf + nd;                    // n*128 f32
    float* h      = sbuf + nd;                    // n*128 f32
    __half* kvh   = (__half*)(h + nd);            // n*256 fp16 (interleaved kv pairs)
    float* bias_cat = (float*)(kvh + (size_t)n * 256);         // 512
    unsigned short* Wph = (unsigned short*)(bias_cat + 512);   // 65536
    unsigned short* Wpl = Wph + 65536;                         // 65536
    int2* epack   = (int2*)(Wpl + 65536);         // E (8B-aligned)
    int* cnt      = (int*)(epack + E);            // n       (8-aligned, n even)
    int* row_ptr  = cnt + n;                      // n+1 (+1 pad) -> 8-aligned
    int* cursor   = row_ptr + n + 2;              // n       (8-aligned)
    int* bsum     = cursor + n;                   // B
    int* boff     = bsum + 256;                   // B
    float* gsums  = (float*)(boff + 256);         // G*128
    float* gcnt   = gsums + (size_t)G * HD;       // G

    const int* srcI = ei;
    const int* dstI = ei + E;

    hipMemsetAsync(cnt, 0, (size_t)n * sizeof(int), stream);
    hipMemsetAsync(gsums, 0, ((size_t)G * HD + G) * sizeof(float), stream);

    hist_kernel<<<(E + 255) / 256, 256, 0, stream>>>(dstI, cnt, E);
    scanA_kernel<<<B, 256, 0, stream>>>(cnt, row_ptr, bsum, n);
    scanB_kernel<<<1, 256, 0, stream>>>(bsum, boff, B);
    scanC_kernel<<<B, 256, 0, stream>>>(row_ptr, cursor, boff, n, E);
    scatter_kernel<<<(E + 255) / 256, 256, 0, stream>>>(dstI, srcI, eattr, cursor, epack, E);

    pack_kernel<<<256, 256, 0, stream>>>(l1_Wq, l1_Wk, l1_Wv, l1_Ws,
                                         l1_bq, l1_bk, l1_bv, l1_bs,
                                         Wph, Wpl, bias_cat);

    attn0_kernel<<<(n + 3) / 4, 256, 0, stream>>>(
        x, l0_Wq, l0_bq, l0_Wk, l0_bk, l0_Wv, l0_bv, l0_We, l0_Ws, l0_bs,
        epack, row_ptr, h, n);

    lin1_mfma<<<dim3((n + 63) / 64, 2), 256, 0, stream>>>(
        h, Wph, Wpl, bias_cat, qbuf, kvh, sbuf, n);
    attn_kernel<<<(n + 3) / 4, 256, 0, stream>>>(
        qbuf, kvh, sbuf, l1_We, epack, row_ptr, h, n);

    pool_kernel<<<(n + 63) / 64, 128, 0, stream>>>(h, batch, gsums, gcnt, n);
    cls_kernel<<<G, 128, 0, stream>>>(gsums, gcnt, cW1, cb1, cW2, cb2, (float*)d_out);
}